// Round 1
// baseline (4425.851 us; speedup 1.0000x reference)
//
#include <hip/hip_runtime.h>
#include <math.h>

#define BN_EPS 1e-5f

// ---------------- edge dtype handling (int32 vs int64) ----------------
__device__ __forceinline__ int edge_at(const void* ei, int idx, int is64) {
    if (is64) return (int)((const long long*)ei)[idx];
    return ((const int*)ei)[idx];
}

// Detect int64 edge_index: for non-negative values < 2^31, every high 32-bit
// word is 0. Probability of 64 consecutive random int32 indices all being 0
// is ~0, so this is a safe discriminator.
__global__ void detect_kernel(const void* ei, int* flag) {
    const int* p = (const int*)ei;
    int f = 1;
    for (int i = 0; i < 64; i++)
        if (p[2 * i + 1] != 0) { f = 0; break; }
    *flag = f;
}

// ---------------- degree / norm ----------------
__global__ void init_kernel(float* deg, double* scal, int n) {
    int i = blockIdx.x * 256 + threadIdx.x;
    if (i < n) deg[i] = 1.0f;                      // self-loop contributes 1
    if (blockIdx.x == 0 && threadIdx.x == 0) { scal[0] = 0.0; scal[1] = 0.0; }
}

__global__ void deg_kernel(const void* ei, const int* flag, float* deg, int E) {
    int e = blockIdx.x * 256 + threadIdx.x;
    if (e >= E) return;
    int is64 = *flag;
    int d = edge_at(ei, E + e, is64);
    atomicAdd(&deg[d], 1.0f);
}

__global__ void dinv_kernel(float* deg, int n) {
    int i = blockIdx.x * 256 + threadIdx.x;
    if (i < n) deg[i] = rsqrtf(fmaxf(deg[i], 1.0f));
}

// ---------------- GEMM: out = (X @ W) * dinv[row], dual-write ----------------
// X: [M,128], W: [128,128]. BM=64, 256 threads, K-tiled by 16.
// out1 = hs (gather source), out2 = scatter accumulator init (self-loop term).
// NOTE: out2 may alias X (in-place overwrite of own rows after k-loop) — safe:
// each row is read only by its owning block, and all reads precede the epilogue.
__global__ __launch_bounds__(256) void gemm128_kernel(
    const float* X, const float* W, const float* __restrict__ dinv,
    float* out1, float* out2, int M) {
    __shared__ float As[16][68];    // transposed tile As[k][row], pad 68 for banks
    __shared__ float Bs[16][128];
    const int t  = threadIdx.x;
    const int r0 = blockIdx.x * 64;
    const int tc = t & 31;          // col group: cols tc*4..tc*4+3
    const int tr = t >> 5;          // row group: rows tr*8..tr*8+7
    float acc[8][4];
    #pragma unroll
    for (int i = 0; i < 8; i++)
        acc[i][0] = acc[i][1] = acc[i][2] = acc[i][3] = 0.f;

    const int ar = t >> 2;          // 0..63 tile row to load
    const int ac = (t & 3) * 4;     // 0..12 k-offset to load (x4)

    for (int k0 = 0; k0 < 128; k0 += 16) {
        float4 av = make_float4(0.f, 0.f, 0.f, 0.f);
        if (r0 + ar < M)
            av = *(const float4*)&X[(size_t)(r0 + ar) * 128 + k0 + ac];
        As[ac + 0][ar] = av.x;
        As[ac + 1][ar] = av.y;
        As[ac + 2][ar] = av.z;
        As[ac + 3][ar] = av.w;
        #pragma unroll
        for (int i = 0; i < 2; i++) {
            int f = t + i * 256;
            int br = f >> 5, bc = (f & 31) * 4;
            *(float4*)&Bs[br][bc] = *(const float4*)&W[(size_t)(k0 + br) * 128 + bc];
        }
        __syncthreads();
        #pragma unroll
        for (int kk = 0; kk < 16; kk++) {
            float4 bv = *(const float4*)&Bs[kk][tc * 4];
            float4 a0 = *(const float4*)&As[kk][tr * 8];
            float4 a1 = *(const float4*)&As[kk][tr * 8 + 4];
            float a[8] = {a0.x, a0.y, a0.z, a0.w, a1.x, a1.y, a1.z, a1.w};
            #pragma unroll
            for (int i = 0; i < 8; i++) {
                acc[i][0] = fmaf(a[i], bv.x, acc[i][0]);
                acc[i][1] = fmaf(a[i], bv.y, acc[i][1]);
                acc[i][2] = fmaf(a[i], bv.z, acc[i][2]);
                acc[i][3] = fmaf(a[i], bv.w, acc[i][3]);
            }
        }
        __syncthreads();
    }
    #pragma unroll
    for (int i = 0; i < 8; i++) {
        int r = r0 + tr * 8 + i;
        if (r < M) {
            float s = dinv[r];
            float4 v = make_float4(acc[i][0] * s, acc[i][1] * s,
                                   acc[i][2] * s, acc[i][3] * s);
            *(float4*)&out1[(size_t)r * 128 + tc * 4] = v;
            *(float4*)&out2[(size_t)r * 128 + tc * 4] = v;
        }
    }
}

// ---------------- edge scatter: S[dst] += hs[src] (atomics) ----------------
// 32 threads per edge, float4 gather + 4 atomicAdds each.
__global__ __launch_bounds__(256) void scatter_kernel(
    const void* ei, const int* flag, const float* hs, float* S, int E) {
    int gid = blockIdx.x * 256 + threadIdx.x;
    if (gid >= E * 32) return;
    int is64 = *flag;
    int e = gid >> 5;
    int p = (gid & 31) * 4;
    int s = edge_at(ei, e, is64);
    int d = edge_at(ei, E + e, is64);
    float4 v = *(const float4*)&hs[(size_t)s * 128 + p];
    float* dp = &S[(size_t)d * 128 + p];
    atomicAdd(dp + 0, v.x);
    atomicAdd(dp + 1, v.y);
    atomicAdd(dp + 2, v.z);
    atomicAdd(dp + 3, v.w);
}

// ---------------- finalize: h = relu(bn(relu(dinv*S + b))) ----------------
__global__ __launch_bounds__(256) void finalize_kernel(
    const float* __restrict__ S, const float* __restrict__ dinv,
    const float* __restrict__ b, const float* __restrict__ g,
    const float* __restrict__ be, const float* __restrict__ m,
    const float* __restrict__ v, float* __restrict__ h, int M) {
    int idx = blockIdx.x * 256 + threadIdx.x;     // over M*32 float4s
    if (idx >= M * 32) return;
    int row = idx >> 5;
    int c4  = (idx & 31) * 4;
    float di = dinv[row];
    float4 sv = *(const float4*)&S[(size_t)row * 128 + c4];
    float o[4] = {sv.x, sv.y, sv.z, sv.w};
    float r[4];
    #pragma unroll
    for (int j = 0; j < 4; j++) {
        int c = c4 + j;
        float t = fmaxf(di * o[j] + b[c], 0.f);
        float sc = g[c] * rsqrtf(v[c] + BN_EPS);
        t = (t - m[c]) * sc + be[c];
        r[j] = fmaxf(t, 0.f);
    }
    *(float4*)&h[(size_t)row * 128 + c4] = make_float4(r[0], r[1], r[2], r[3]);
}

// ---------------- output GEMM: out = H @ W3 + b3, [M,128]x[128,40] ----------
// 256 rows/block, 4 rows x 10 cols per thread, W3 fully in LDS.
__global__ __launch_bounds__(256) void gemm_out_kernel(
    const float* __restrict__ H, const float* __restrict__ W3,
    const float* __restrict__ b3, float* __restrict__ out, int M) {
    __shared__ float Hs[256][20];   // 16-k tile, pad 20 for banks
    __shared__ float Ws[128][40];
    const int t  = threadIdx.x;
    const int r0 = blockIdx.x * 256;
    #pragma unroll
    for (int i = 0; i < 5; i++) {
        int f = t + i * 256;        // 1280 float4 = full W3
        ((float4*)Ws)[f] = ((const float4*)W3)[f];
    }
    const int rg = t >> 2;          // 0..63
    const int cb = (t & 3) * 10;    // col base
    float acc[4][10];
    #pragma unroll
    for (int i = 0; i < 4; i++)
        #pragma unroll
        for (int j = 0; j < 10; j++) acc[i][j] = 0.f;

    for (int k0 = 0; k0 < 128; k0 += 16) {
        __syncthreads();            // also covers initial Ws store
        #pragma unroll
        for (int i = 0; i < 4; i++) {
            int f = t + i * 256;    // 1024 float4 = 256x16 tile
            int r = f >> 2, c = (f & 3) * 4;
            float4 hv = make_float4(0.f, 0.f, 0.f, 0.f);
            if (r0 + r < M)
                hv = *(const float4*)&H[(size_t)(r0 + r) * 128 + k0 + c];
            *(float4*)&Hs[r][c] = hv;
        }
        __syncthreads();
        #pragma unroll
        for (int k4 = 0; k4 < 4; k4++) {
            float hv[4][4];
            #pragma unroll
            for (int i = 0; i < 4; i++) {
                float4 h4 = *(const float4*)&Hs[rg + 64 * i][k4 * 4];
                hv[i][0] = h4.x; hv[i][1] = h4.y; hv[i][2] = h4.z; hv[i][3] = h4.w;
            }
            #pragma unroll
            for (int q = 0; q < 4; q++) {
                int k = k0 + k4 * 4 + q;
                float w[10];
                #pragma unroll
                for (int j = 0; j < 5; j++) {
                    float2 w2 = *(const float2*)&Ws[k][cb + 2 * j];
                    w[2 * j] = w2.x; w[2 * j + 1] = w2.y;
                }
                #pragma unroll
                for (int i = 0; i < 4; i++)
                    #pragma unroll
                    for (int j = 0; j < 10; j++)
                        acc[i][j] = fmaf(hv[i][q], w[j], acc[i][j]);
            }
        }
    }
    #pragma unroll
    for (int i = 0; i < 4; i++) {
        int row = r0 + rg + 64 * i;
        if (row < M) {
            #pragma unroll
            for (int j = 0; j < 10; j++)
                out[(size_t)row * 40 + cb + j] = acc[i][j] + b3[cb + j];
        }
    }
}

// ---------------- log_softmax (in place) + var partial sums ----------------
__global__ __launch_bounds__(256) void lsm_kernel(float* out, double* scal, int M) {
    const int wid  = threadIdx.x >> 6;
    const int lane = threadIdx.x & 63;
    float s1 = 0.f, s2 = 0.f;
    for (int r = blockIdx.x * 4 + wid; r < M; r += gridDim.x * 4) {
        size_t base = (size_t)r * 40;
        float x = (lane < 40) ? out[base + lane] : -INFINITY;
        float mx = x;
        #pragma unroll
        for (int o = 32; o; o >>= 1) mx = fmaxf(mx, __shfl_xor(mx, o));
        float e = (lane < 40) ? expf(x - mx) : 0.f;
        float se = e;
        #pragma unroll
        for (int o = 32; o; o >>= 1) se += __shfl_xor(se, o);
        float ls = mx + logf(se);
        if (lane < 40) {
            out[base + lane] = x - ls;
            s1 += x;
            s2 += x * x;
        }
    }
    #pragma unroll
    for (int o = 32; o; o >>= 1) { s1 += __shfl_xor(s1, o); s2 += __shfl_xor(s2, o); }
    __shared__ double sh1[4], sh2[4];
    if (lane == 0) { sh1[wid] = (double)s1; sh2[wid] = (double)s2; }
    __syncthreads();
    if (threadIdx.x == 0) {
        atomicAdd(&scal[0], sh1[0] + sh1[1] + sh1[2] + sh1[3]);
        atomicAdd(&scal[1], sh2[0] + sh2[1] + sh2[2] + sh2[3]);
    }
}

__global__ void var_kernel(const double* scal, float* out, long long nn, long long off) {
    double s1 = scal[0], s2 = scal[1];
    out[off] = (float)((s2 - s1 * s1 / (double)nn) / (double)(nn - 1));
}

// ---------------- launch ----------------
extern "C" void kernel_launch(void* const* d_in, const int* in_sizes, int n_in,
                              void* d_out, int out_size, void* d_ws, size_t ws_size,
                              hipStream_t stream) {
    const float* x   = (const float*)d_in[0];
    const void*  ei  = d_in[1];
    const float* W1  = (const float*)d_in[2];
    const float* b1  = (const float*)d_in[3];
    const float* g1  = (const float*)d_in[4];
    const float* be1 = (const float*)d_in[5];
    const float* m1  = (const float*)d_in[6];
    const float* v1  = (const float*)d_in[7];
    const float* W2  = (const float*)d_in[8];
    const float* b2  = (const float*)d_in[9];
    const float* g2  = (const float*)d_in[10];
    const float* be2 = (const float*)d_in[11];
    const float* m2  = (const float*)d_in[12];
    const float* v2  = (const float*)d_in[13];
    const float* W3  = (const float*)d_in[14];
    const float* b3  = (const float*)d_in[15];

    const int n = in_sizes[0] / 128;   // 169343 nodes
    const int E = in_sizes[1] / 2;     // 1166243 edges
    float* out = (float*)d_out;

    // workspace layout: A[N*128] | B[N*128] | dinv[N pad] | 2 doubles | flag
    size_t nh = (size_t)n * 128;
    float*  A    = (float*)d_ws;
    float*  B    = A + nh;
    float*  dinv = B + nh;
    size_t  dpad = ((size_t)n + 3) & ~(size_t)3;
    double* scal = (double*)(dinv + dpad);
    int*    flag = (int*)(scal + 2);

    const int nb_n   = (n + 255) / 256;
    const int nb_e   = (E + 255) / 256;
    const int nb_g   = (n + 63) / 64;
    const int nb_sc  = (E * 32 + 255) / 256;
    const int nb_fin = (n * 32 + 255) / 256;
    const int nb_g3  = (n + 255) / 256;

    detect_kernel<<<1, 1, 0, stream>>>(ei, flag);
    init_kernel<<<nb_n, 256, 0, stream>>>(dinv, scal, n);      // dinv holds deg first
    deg_kernel<<<nb_e, 256, 0, stream>>>(ei, flag, dinv, E);
    dinv_kernel<<<nb_n, 256, 0, stream>>>(dinv, n);

    // layer 1: A = hs1, B = S1 (init to hs1 = self-loop term)
    gemm128_kernel<<<nb_g, 256, 0, stream>>>(x, W1, dinv, A, B, n);
    scatter_kernel<<<nb_sc, 256, 0, stream>>>(ei, flag, A, B, E);
    finalize_kernel<<<nb_fin, 256, 0, stream>>>(B, dinv, b1, g1, be1, m1, v1, A, n); // A = h1

    // layer 2: B = hs2, A = S2 (in-place overwrite of h1 rows in epilogue)
    gemm128_kernel<<<nb_g, 256, 0, stream>>>(A, W2, dinv, B, A, n);
    scatter_kernel<<<nb_sc, 256, 0, stream>>>(ei, flag, B, A, E);
    finalize_kernel<<<nb_fin, 256, 0, stream>>>(A, dinv, b2, g2, be2, m2, v2, B, n); // B = h2

    // output layer + fused epilogues
    gemm_out_kernel<<<nb_g3, 256, 0, stream>>>(B, W3, b3, out, n);
    lsm_kernel<<<2048, 256, 0, stream>>>(out, scal, n);
    var_kernel<<<1, 1, 0, stream>>>(scal, out, (long long)n * 40, (long long)n * 40);
}

// Round 2
// 855.502 us; speedup vs baseline: 5.1734x; 5.1734x over previous
//
#include <hip/hip_runtime.h>
#include <math.h>

#define BN_EPS 1e-5f

// ---------------- edge dtype handling (int32 vs int64) ----------------
__device__ __forceinline__ int edge_at(const void* ei, long long idx, int is64) {
    if (is64) return (int)((const long long*)ei)[idx];
    return ((const int*)ei)[idx];
}

// Detect int64 edge_index: for non-negative values < 2^31, every high 32-bit
// word is 0 across 64 consecutive entries only if the array is int64.
__global__ void detect_kernel(const void* ei, int* flag) {
    const int* p = (const int*)ei;
    int f = 1;
    for (int i = 0; i < 64; i++)
        if (p[2 * i + 1] != 0) { f = 0; break; }
    *flag = f;
}

// ---------------- init: zero int-degrees + scalars ----------------
__global__ void init_kernel(int* deg_i, double* scal, int n) {
    int i = blockIdx.x * 256 + threadIdx.x;
    if (i < n) deg_i[i] = 0;
    if (blockIdx.x == 0 && threadIdx.x == 0) { scal[0] = 0.0; scal[1] = 0.0; }
}

__global__ void degi_kernel(const void* ei, const int* flag, int* deg_i, int E) {
    int e = blockIdx.x * 256 + threadIdx.x;
    if (e >= E) return;
    int is64 = *flag;
    int d = edge_at(ei, (long long)E + e, is64);
    atomicAdd(&deg_i[d], 1);
}

__global__ void dinv_kernel(const int* __restrict__ deg_i, float* dinv, int n) {
    int i = blockIdx.x * 256 + threadIdx.x;
    if (i < n) dinv[i] = rsqrtf((float)(deg_i[i] + 1));   // +1 self-loop, >=1
}

// ---------------- exclusive scan (3 kernels, 2048 elems/block) ----------------
__global__ __launch_bounds__(256) void scan1_kernel(
    const int* __restrict__ in, int* __restrict__ excl, int* bsum, int n) {
    __shared__ int sh[256];
    const int tid = threadIdx.x;
    const int base = blockIdx.x * 2048 + tid * 8;
    int v[8];
    #pragma unroll
    for (int i = 0; i < 8; i++) v[i] = (base + i < n) ? in[base + i] : 0;
    int tsum = 0;
    #pragma unroll
    for (int i = 0; i < 8; i++) { int t = v[i]; v[i] = tsum; tsum += t; }
    sh[tid] = tsum;
    __syncthreads();
    for (int off = 1; off < 256; off <<= 1) {
        int t = 0;
        if (tid >= off) t = sh[tid - off];
        __syncthreads();
        if (tid >= off) sh[tid] += t;
        __syncthreads();
    }
    int texcl = sh[tid] - tsum;
    #pragma unroll
    for (int i = 0; i < 8; i++)
        if (base + i < n) excl[base + i] = texcl + v[i];
    if (tid == 255 && bsum) bsum[blockIdx.x] = sh[255];
}

__global__ void scan3_kernel(int* rowptr, const int* __restrict__ boff,
                             int* cursor, int n, int E) {
    int i = blockIdx.x * 256 + threadIdx.x;
    if (i < n) {
        int val = rowptr[i] + boff[i >> 11];
        rowptr[i] = val;
        cursor[i] = val;
    }
    if (i == 0) rowptr[n] = E;
}

__global__ void fill_kernel(const void* ei, const int* flag,
                            int* cursor, int* col, int E) {
    int e = blockIdx.x * 256 + threadIdx.x;
    if (e >= E) return;
    int is64 = *flag;
    int s = edge_at(ei, e, is64);
    int d = edge_at(ei, (long long)E + e, is64);
    int pos = atomicAdd(&cursor[d], 1);
    col[pos] = s;
}

// ---------------- GEMM: out = (X @ W) * dinv[row] ----------------
// X: [M,128], W: [128,128]. BM=64, 256 threads, K-tiled by 16.
__global__ __launch_bounds__(256) void gemm128_kernel(
    const float* __restrict__ X, const float* __restrict__ W,
    const float* __restrict__ dinv, float* __restrict__ out, int M) {
    __shared__ float As[16][68];    // transposed tile As[k][row]
    __shared__ float Bs[16][128];
    const int t  = threadIdx.x;
    const int r0 = blockIdx.x * 64;
    const int tc = t & 31;
    const int tr = t >> 5;
    float acc[8][4];
    #pragma unroll
    for (int i = 0; i < 8; i++)
        acc[i][0] = acc[i][1] = acc[i][2] = acc[i][3] = 0.f;

    const int ar = t >> 2;
    const int ac = (t & 3) * 4;

    for (int k0 = 0; k0 < 128; k0 += 16) {
        float4 av = make_float4(0.f, 0.f, 0.f, 0.f);
        if (r0 + ar < M)
            av = *(const float4*)&X[(size_t)(r0 + ar) * 128 + k0 + ac];
        As[ac + 0][ar] = av.x;
        As[ac + 1][ar] = av.y;
        As[ac + 2][ar] = av.z;
        As[ac + 3][ar] = av.w;
        #pragma unroll
        for (int i = 0; i < 2; i++) {
            int f = t + i * 256;
            int br = f >> 5, bc = (f & 31) * 4;
            *(float4*)&Bs[br][bc] = *(const float4*)&W[(size_t)(k0 + br) * 128 + bc];
        }
        __syncthreads();
        #pragma unroll
        for (int kk = 0; kk < 16; kk++) {
            float4 bv = *(const float4*)&Bs[kk][tc * 4];
            float4 a0 = *(const float4*)&As[kk][tr * 8];
            float4 a1 = *(const float4*)&As[kk][tr * 8 + 4];
            float a[8] = {a0.x, a0.y, a0.z, a0.w, a1.x, a1.y, a1.z, a1.w};
            #pragma unroll
            for (int i = 0; i < 8; i++) {
                acc[i][0] = fmaf(a[i], bv.x, acc[i][0]);
                acc[i][1] = fmaf(a[i], bv.y, acc[i][1]);
                acc[i][2] = fmaf(a[i], bv.z, acc[i][2]);
                acc[i][3] = fmaf(a[i], bv.w, acc[i][3]);
            }
        }
        __syncthreads();
    }
    #pragma unroll
    for (int i = 0; i < 8; i++) {
        int r = r0 + tr * 8 + i;
        if (r < M) {
            float s = dinv[r];
            *(float4*)&out[(size_t)r * 128 + tc * 4] =
                make_float4(acc[i][0] * s, acc[i][1] * s,
                            acc[i][2] * s, acc[i][3] * s);
        }
    }
}

// ---------------- fused pull-aggregate + bias + relu + BN + relu ----------
// One wave (64 lanes) per node; lane owns 2 channels (float2 = 8B).
// out[i] = relu(bn(relu(dinv[i] * (hs[i] + sum_{s in N(i)} hs[s]) + b)))
__global__ __launch_bounds__(256) void agg_kernel(
    const float* __restrict__ hs, const int* __restrict__ rowptr,
    const int* __restrict__ col, const float* __restrict__ dinv,
    const float* __restrict__ b, const float* __restrict__ g,
    const float* __restrict__ be, const float* __restrict__ m,
    const float* __restrict__ v, float* __restrict__ h, int M) {
    const int node = blockIdx.x * 4 + (threadIdx.x >> 6);
    if (node >= M) return;
    const int lane = threadIdx.x & 63;
    const int c = lane * 2;

    float2 acc = *(const float2*)&hs[(size_t)node * 128 + c];  // self-loop term
    const int beg = rowptr[node], end = rowptr[node + 1];
    int j = beg;
    // 2-deep software pipeline on the neighbor index
    int s0 = (j < end) ? col[j] : 0;
    for (; j < end; ) {
        int s1 = (j + 1 < end) ? col[j + 1] : 0;
        float2 vv = *(const float2*)&hs[(size_t)s0 * 128 + c];
        acc.x += vv.x; acc.y += vv.y;
        s0 = s1;
        ++j;
    }
    const float di = dinv[node];
    float o[2] = {acc.x, acc.y};
    float r[2];
    #pragma unroll
    for (int jj = 0; jj < 2; jj++) {
        int cc = c + jj;
        float t = fmaxf(di * o[jj] + b[cc], 0.f);
        t = (t - m[cc]) * (g[cc] * rsqrtf(v[cc] + BN_EPS)) + be[cc];
        r[jj] = fmaxf(t, 0.f);
    }
    *(float2*)&h[(size_t)node * 128 + c] = make_float2(r[0], r[1]);
}

// ---------------- output GEMM: out = H @ W3 + b3, [M,128]x[128,40] ----------
__global__ __launch_bounds__(256) void gemm_out_kernel(
    const float* __restrict__ H, const float* __restrict__ W3,
    const float* __restrict__ b3, float* __restrict__ out, int M) {
    __shared__ float Hs[256][20];
    __shared__ float Ws[128][40];
    const int t  = threadIdx.x;
    const int r0 = blockIdx.x * 256;
    #pragma unroll
    for (int i = 0; i < 5; i++) {
        int f = t + i * 256;
        ((float4*)Ws)[f] = ((const float4*)W3)[f];
    }
    const int rg = t >> 2;
    const int cb = (t & 3) * 10;
    float acc[4][10];
    #pragma unroll
    for (int i = 0; i < 4; i++)
        #pragma unroll
        for (int j = 0; j < 10; j++) acc[i][j] = 0.f;

    for (int k0 = 0; k0 < 128; k0 += 16) {
        __syncthreads();
        #pragma unroll
        for (int i = 0; i < 4; i++) {
            int f = t + i * 256;
            int r = f >> 2, c = (f & 3) * 4;
            float4 hv = make_float4(0.f, 0.f, 0.f, 0.f);
            if (r0 + r < M)
                hv = *(const float4*)&H[(size_t)(r0 + r) * 128 + k0 + c];
            *(float4*)&Hs[r][c] = hv;
        }
        __syncthreads();
        #pragma unroll
        for (int k4 = 0; k4 < 4; k4++) {
            float hv[4][4];
            #pragma unroll
            for (int i = 0; i < 4; i++) {
                float4 h4 = *(const float4*)&Hs[rg + 64 * i][k4 * 4];
                hv[i][0] = h4.x; hv[i][1] = h4.y; hv[i][2] = h4.z; hv[i][3] = h4.w;
            }
            #pragma unroll
            for (int q = 0; q < 4; q++) {
                int k = k0 + k4 * 4 + q;
                float w[10];
                #pragma unroll
                for (int j = 0; j < 5; j++) {
                    float2 w2 = *(const float2*)&Ws[k][cb + 2 * j];
                    w[2 * j] = w2.x; w[2 * j + 1] = w2.y;
                }
                #pragma unroll
                for (int i = 0; i < 4; i++)
                    #pragma unroll
                    for (int j = 0; j < 10; j++)
                        acc[i][j] = fmaf(hv[i][q], w[j], acc[i][j]);
            }
        }
    }
    #pragma unroll
    for (int i = 0; i < 4; i++) {
        int row = r0 + rg + 64 * i;
        if (row < M) {
            #pragma unroll
            for (int j = 0; j < 10; j++)
                out[(size_t)row * 40 + cb + j] = acc[i][j] + b3[cb + j];
        }
    }
}

// ---------------- log_softmax (in place) + var partial sums ----------------
__global__ __launch_bounds__(256) void lsm_kernel(float* out, double* scal, int M) {
    const int wid  = threadIdx.x >> 6;
    const int lane = threadIdx.x & 63;
    float s1 = 0.f, s2 = 0.f;
    for (int r = blockIdx.x * 4 + wid; r < M; r += gridDim.x * 4) {
        size_t base = (size_t)r * 40;
        float x = (lane < 40) ? out[base + lane] : -INFINITY;
        float mx = x;
        #pragma unroll
        for (int o = 32; o; o >>= 1) mx = fmaxf(mx, __shfl_xor(mx, o));
        float e = (lane < 40) ? expf(x - mx) : 0.f;
        float se = e;
        #pragma unroll
        for (int o = 32; o; o >>= 1) se += __shfl_xor(se, o);
        float ls = mx + logf(se);
        if (lane < 40) {
            out[base + lane] = x - ls;
            s1 += x;
            s2 += x * x;
        }
    }
    #pragma unroll
    for (int o = 32; o; o >>= 1) { s1 += __shfl_xor(s1, o); s2 += __shfl_xor(s2, o); }
    __shared__ double sh1[4], sh2[4];
    if (lane == 0) { sh1[wid] = (double)s1; sh2[wid] = (double)s2; }
    __syncthreads();
    if (threadIdx.x == 0) {
        atomicAdd(&scal[0], sh1[0] + sh1[1] + sh1[2] + sh1[3]);
        atomicAdd(&scal[1], sh2[0] + sh2[1] + sh2[2] + sh2[3]);
    }
}

__global__ void var_kernel(const double* scal, float* out, long long nn, long long off) {
    double s1 = scal[0], s2 = scal[1];
    out[off] = (float)((s2 - s1 * s1 / (double)nn) / (double)(nn - 1));
}

// ---------------- launch ----------------
extern "C" void kernel_launch(void* const* d_in, const int* in_sizes, int n_in,
                              void* d_out, int out_size, void* d_ws, size_t ws_size,
                              hipStream_t stream) {
    const float* x   = (const float*)d_in[0];
    const void*  ei  = d_in[1];
    const float* W1  = (const float*)d_in[2];
    const float* b1  = (const float*)d_in[3];
    const float* g1  = (const float*)d_in[4];
    const float* be1 = (const float*)d_in[5];
    const float* m1  = (const float*)d_in[6];
    const float* v1  = (const float*)d_in[7];
    const float* W2  = (const float*)d_in[8];
    const float* b2  = (const float*)d_in[9];
    const float* g2  = (const float*)d_in[10];
    const float* be2 = (const float*)d_in[11];
    const float* m2  = (const float*)d_in[12];
    const float* v2  = (const float*)d_in[13];
    const float* W3  = (const float*)d_in[14];
    const float* b3  = (const float*)d_in[15];

    const int n = in_sizes[0] / 128;   // 169343 nodes
    const int E = in_sizes[1] / 2;     // 1166243 edges
    float* out = (float*)d_out;

    // workspace layout (16B-aligned chunks):
    // scal[2] dbl | A[nh] | B[nh] | dinv[npad] | deg_i[npad] | rowptr[npad+4]
    // | cursor[npad] | bsum[128] | boff[128] | flag[4] | col[E]
    size_t nh   = (size_t)n * 128;
    size_t npad = ((size_t)n + 3) & ~(size_t)3;
    double* scal   = (double*)d_ws;
    float*  A      = (float*)(scal + 2) + 2;     // keep 16B alignment
    float*  B      = A + nh;
    float*  dinv   = B + nh;
    int*    deg_i  = (int*)(dinv + npad);
    int*    rowptr = deg_i + npad;
    int*    cursor = rowptr + npad + 4;
    int*    bsum   = cursor + npad;
    int*    boff   = bsum + 128;
    int*    flag   = boff + 128;
    int*    col    = flag + 4;

    const int nb_n   = (n + 255) / 256;
    const int nb_e   = (E + 255) / 256;
    const int nb_g   = (n + 63) / 64;
    const int nb_agg = (n + 3) / 4;
    const int nb_g3  = (n + 255) / 256;
    const int nb_sc  = (n + 2047) / 2048;        // scan blocks (83)

    detect_kernel<<<1, 1, 0, stream>>>(ei, flag);
    init_kernel<<<nb_n, 256, 0, stream>>>(deg_i, scal, n);
    degi_kernel<<<nb_e, 256, 0, stream>>>(ei, flag, deg_i, E);
    dinv_kernel<<<nb_n, 256, 0, stream>>>(deg_i, dinv, n);

    // CSR build: exclusive scan of degrees -> rowptr, then fill col by dst
    scan1_kernel<<<nb_sc, 256, 0, stream>>>(deg_i, rowptr, bsum, n);
    scan1_kernel<<<1, 256, 0, stream>>>(bsum, boff, nullptr, nb_sc);
    scan3_kernel<<<nb_n, 256, 0, stream>>>(rowptr, boff, cursor, n, E);
    fill_kernel<<<nb_e, 256, 0, stream>>>(ei, flag, cursor, col, E);

    // layer 1
    gemm128_kernel<<<nb_g, 256, 0, stream>>>(x, W1, dinv, A, n);
    agg_kernel<<<nb_agg, 256, 0, stream>>>(A, rowptr, col, dinv,
                                           b1, g1, be1, m1, v1, B, n);
    // layer 2
    gemm128_kernel<<<nb_g, 256, 0, stream>>>(B, W2, dinv, A, n);
    agg_kernel<<<nb_agg, 256, 0, stream>>>(A, rowptr, col, dinv,
                                           b2, g2, be2, m2, v2, B, n);
    // output layer + fused epilogues
    gemm_out_kernel<<<nb_g3, 256, 0, stream>>>(B, W3, b3, out, n);
    lsm_kernel<<<2048, 256, 0, stream>>>(out, scal, n);
    var_kernel<<<1, 1, 0, stream>>>(scal, out, (long long)n * 40, (long long)n * 40);
}

// Round 5
// 801.719 us; speedup vs baseline: 5.5205x; 1.0671x over previous
//
#include <hip/hip_runtime.h>
#include <math.h>

#define BN_EPS 1e-5f

typedef __attribute__((ext_vector_type(8))) short short8;
typedef __attribute__((ext_vector_type(4))) float f32x4;

__device__ __forceinline__ unsigned short f2bf(float f) {
    unsigned u = __float_as_uint(f);
    u += 0x7fff + ((u >> 16) & 1);          // round-to-nearest-even
    return (unsigned short)(u >> 16);
}
__device__ __forceinline__ float bf2f(unsigned short h) {
    return __uint_as_float(((unsigned)h) << 16);
}

// ---------------- edge dtype handling (int32 vs int64) ----------------
__device__ __forceinline__ int edge_at(const void* ei, long long idx, int is64) {
    if (is64) return (int)((const long long*)ei)[idx];
    return ((const int*)ei)[idx];
}

__global__ void detect_kernel(const void* ei, int* flag) {
    const int* p = (const int*)ei;
    int f = 1;
    for (int i = 0; i < 64; i++)
        if (p[2 * i + 1] != 0) { f = 0; break; }
    *flag = f;
}

// ---------------- init: zero int-degrees + scalars ----------------
__global__ void init_kernel(int* deg_i, double* scal, int n) {
    int i = blockIdx.x * 256 + threadIdx.x;
    if (i < n) deg_i[i] = 0;
    if (blockIdx.x == 0 && threadIdx.x == 0) { scal[0] = 0.0; scal[1] = 0.0; }
}

__global__ void degi_kernel(const void* ei, const int* flag, int* deg_i, int E) {
    int e = blockIdx.x * 256 + threadIdx.x;
    if (e >= E) return;
    int is64 = *flag;
    int d = edge_at(ei, (long long)E + e, is64);
    atomicAdd(&deg_i[d], 1);
}

__global__ void dinv_kernel(const int* __restrict__ deg_i, float* dinv, int n) {
    int i = blockIdx.x * 256 + threadIdx.x;
    if (i < n) dinv[i] = rsqrtf((float)(deg_i[i] + 1));
}

// ---------------- exclusive scan (3 kernels, 2048 elems/block) -------------
__global__ __launch_bounds__(256) void scan1_kernel(
    const int* __restrict__ in, int* __restrict__ excl, int* bsum, int n) {
    __shared__ int sh[256];
    const int tid = threadIdx.x;
    const int base = blockIdx.x * 2048 + tid * 8;
    int v[8];
    #pragma unroll
    for (int i = 0; i < 8; i++) v[i] = (base + i < n) ? in[base + i] : 0;
    int tsum = 0;
    #pragma unroll
    for (int i = 0; i < 8; i++) { int t = v[i]; v[i] = tsum; tsum += t; }
    sh[tid] = tsum;
    __syncthreads();
    for (int off = 1; off < 256; off <<= 1) {
        int t = 0;
        if (tid >= off) t = sh[tid - off];
        __syncthreads();
        if (tid >= off) sh[tid] += t;
        __syncthreads();
    }
    int texcl = sh[tid] - tsum;
    #pragma unroll
    for (int i = 0; i < 8; i++)
        if (base + i < n) excl[base + i] = texcl + v[i];
    if (tid == 255 && bsum) bsum[blockIdx.x] = sh[255];
}

__global__ void scan3_kernel(int* rowptr, const int* __restrict__ boff,
                             int* cursor, int n, int E) {
    int i = blockIdx.x * 256 + threadIdx.x;
    if (i < n) {
        int val = rowptr[i] + boff[i >> 11];
        rowptr[i] = val;
        cursor[i] = val;
    }
    if (i == 0) rowptr[n] = E;
}

__global__ void fill_kernel(const void* ei, const int* flag,
                            int* cursor, int* col, int E) {
    int e = blockIdx.x * 256 + threadIdx.x;
    if (e >= E) return;
    int is64 = *flag;
    int s = edge_at(ei, e, is64);
    int d = edge_at(ei, (long long)E + e, is64);
    int pos = atomicAdd(&cursor[d], 1);
    col[pos] = s;
}

// ---------------- W prep: transpose + bf16 hi/lo split ----------------
// Wth/Wtl are [n][k] (transposed), so B-fragment loads are contiguous in k.
__global__ __launch_bounds__(256) void prep_w_kernel(
    const float* __restrict__ W, unsigned short* __restrict__ Wth,
    unsigned short* __restrict__ Wtl) {
    for (int f = blockIdx.x * 256 + threadIdx.x; f < 128 * 128;
         f += gridDim.x * 256) {
        int k = f >> 7, nn = f & 127;
        float wv = W[f];
        unsigned short h = f2bf(wv);
        float rem = wv - bf2f(h);
        Wth[nn * 128 + k] = h;
        Wtl[nn * 128 + k] = f2bf(rem);
    }
}

// ---------------- MFMA GEMM: out = (X @ W) * dinv[row] ----------------
// fp32 emulated as bf16-split: X@W = Xh@Wh + Xh@Wl + Xl@Wh  (lo*lo dropped).
// 128x128 tile, 4 waves (2x2), 16x16x32 MFMA, K chunked by 32.
#define APAD 40   // padded k-stride (ushorts): 80B rows -> 2-way bank alias max
__global__ __launch_bounds__(256) void gemm_mfma_kernel(
    const float* __restrict__ X, const unsigned short* __restrict__ Wth,
    const unsigned short* __restrict__ Wtl, const float* __restrict__ dinv,
    float* __restrict__ out, int M) {
    __shared__ unsigned short Ah[128 * APAD];
    __shared__ unsigned short Al[128 * APAD];
    __shared__ unsigned short Bh[128 * APAD];
    __shared__ unsigned short Bl[128 * APAD];
    const int t = threadIdx.x;
    const int r0 = blockIdx.x * 128;
    const int w = t >> 6, lane = t & 63;
    const int m0 = (w >> 1) * 64, n0 = (w & 1) * 64;
    const int fr = lane & 15;          // row/col within 16x16 fragment
    const int kb = (lane >> 4) * 8;    // k offset of this lane's 8 elems

    f32x4 acc[4][4];
    #pragma unroll
    for (int i = 0; i < 4; i++)
        #pragma unroll
        for (int j = 0; j < 4; j++) acc[i][j] = (f32x4)0.f;

    for (int k0 = 0; k0 < 128; k0 += 32) {
        // stage A chunk [128 rows][32 k]: fp32 -> hi/lo bf16 inline
        #pragma unroll
        for (int i = 0; i < 4; i++) {
            int f = t + i * 256;               // 0..1023
            int row = f >> 3, kq = (f & 7) * 4;
            float4 v = make_float4(0.f, 0.f, 0.f, 0.f);
            if (r0 + row < M)
                v = *(const float4*)&X[(size_t)(r0 + row) * 128 + k0 + kq];
            unsigned short h0 = f2bf(v.x), h1 = f2bf(v.y),
                           h2 = f2bf(v.z), h3 = f2bf(v.w);
            unsigned short l0 = f2bf(v.x - bf2f(h0)), l1 = f2bf(v.y - bf2f(h1)),
                           l2 = f2bf(v.z - bf2f(h2)), l3 = f2bf(v.w - bf2f(h3));
            int base = row * APAD + kq;
            *(ushort4*)&Ah[base] = make_ushort4(h0, h1, h2, h3);
            *(ushort4*)&Al[base] = make_ushort4(l0, l1, l2, l3);
        }
        // stage W chunk [128 n][32 k] hi/lo (16B copies)
        #pragma unroll
        for (int i = 0; i < 2; i++) {
            int f = t + i * 256;               // 0..511
            int nrow = f >> 2, kq = (f & 3) * 8;
            int gb = nrow * 128 + k0 + kq;
            int lb = nrow * APAD + kq;
            *(float4*)&Bh[lb] = *(const float4*)&Wth[gb];
            *(float4*)&Bl[lb] = *(const float4*)&Wtl[gb];
        }
        __syncthreads();

        short8 a0[4], b0[4], x1[4];
        #pragma unroll
        for (int i = 0; i < 4; i++) {
            a0[i] = *(const short8*)&Ah[(m0 + i * 16 + fr) * APAD + kb];
            b0[i] = *(const short8*)&Bh[(n0 + i * 16 + fr) * APAD + kb];
        }
        #pragma unroll
        for (int i = 0; i < 4; i++)
            #pragma unroll
            for (int j = 0; j < 4; j++)
                acc[i][j] = __builtin_amdgcn_mfma_f32_16x16x32_bf16(
                    a0[i], b0[j], acc[i][j], 0, 0, 0);
        #pragma unroll
        for (int i = 0; i < 4; i++)
            x1[i] = *(const short8*)&Bl[(n0 + i * 16 + fr) * APAD + kb];
        #pragma unroll
        for (int i = 0; i < 4; i++)
            #pragma unroll
            for (int j = 0; j < 4; j++)
                acc[i][j] = __builtin_amdgcn_mfma_f32_16x16x32_bf16(
                    a0[i], x1[j], acc[i][j], 0, 0, 0);
        #pragma unroll
        for (int i = 0; i < 4; i++)
            x1[i] = *(const short8*)&Al[(m0 + i * 16 + fr) * APAD + kb];
        #pragma unroll
        for (int i = 0; i < 4; i++)
            #pragma unroll
            for (int j = 0; j < 4; j++)
                acc[i][j] = __builtin_amdgcn_mfma_f32_16x16x32_bf16(
                    x1[i], b0[j], acc[i][j], 0, 0, 0);
        __syncthreads();
    }

    // epilogue: C/D layout col=lane&15, row=(lane>>4)*4+reg (m89-verified)
    #pragma unroll
    for (int i = 0; i < 4; i++) {
        #pragma unroll
        for (int r = 0; r < 4; r++) {
            int row = r0 + m0 + i * 16 + (lane >> 4) * 4 + r;
            if (row < M) {
                float di = dinv[row];
                #pragma unroll
                for (int j = 0; j < 4; j++)
                    out[(size_t)row * 128 + n0 + j * 16 + fr] = acc[i][j][r] * di;
            }
        }
    }
}

// ---------------- fused pull-aggregate + bias + relu + BN + relu ----------
__global__ __launch_bounds__(256) void agg_kernel(
    const float* __restrict__ hs, const int* __restrict__ rowptr,
    const int* __restrict__ col, const float* __restrict__ dinv,
    const float* __restrict__ b, const float* __restrict__ g,
    const float* __restrict__ be, const float* __restrict__ m,
    const float* __restrict__ v, float* __restrict__ h, int M) {
    const int node = blockIdx.x * 4 + (threadIdx.x >> 6);
    if (node >= M) return;
    const int lane = threadIdx.x & 63;
    const int c = lane * 2;

    float2 acc = *(const float2*)&hs[(size_t)node * 128 + c];  // self-loop
    float2 acc2 = make_float2(0.f, 0.f);
    const int beg = rowptr[node], end = rowptr[node + 1];
    int j = beg;
    for (; j + 1 < end; j += 2) {       // dual accumulators: 2 loads in flight
        int s0 = col[j], s1 = col[j + 1];
        float2 v0 = *(const float2*)&hs[(size_t)s0 * 128 + c];
        float2 v1 = *(const float2*)&hs[(size_t)s1 * 128 + c];
        acc.x += v0.x; acc.y += v0.y;
        acc2.x += v1.x; acc2.y += v1.y;
    }
    if (j < end) {
        int s0 = col[j];
        float2 v0 = *(const float2*)&hs[(size_t)s0 * 128 + c];
        acc.x += v0.x; acc.y += v0.y;
    }
    acc.x += acc2.x; acc.y += acc2.y;

    const float di = dinv[node];
    float r[2];
    #pragma unroll
    for (int jj = 0; jj < 2; jj++) {
        int cc = c + jj;
        float o = (jj == 0) ? acc.x : acc.y;
        float tt = fmaxf(di * o + b[cc], 0.f);
        tt = (tt - m[cc]) * (g[cc] * rsqrtf(v[cc] + BN_EPS)) + be[cc];
        r[jj] = fmaxf(tt, 0.f);
    }
    *(float2*)&h[(size_t)node * 128 + c] = make_float2(r[0], r[1]);
}

// ---------------- output GEMM: out = H @ W3 + b3, [M,128]x[128,40] ----------
__global__ __launch_bounds__(256) void gemm_out_kernel(
    const float* __restrict__ H, const float* __restrict__ W3,
    const float* __restrict__ b3, float* __restrict__ out, int M) {
    __shared__ float Hs[256][20];
    __shared__ float Ws[128][40];
    const int t  = threadIdx.x;
    const int r0 = blockIdx.x * 256;
    #pragma unroll
    for (int i = 0; i < 5; i++) {
        int f = t + i * 256;
        ((float4*)Ws)[f] = ((const float4*)W3)[f];
    }
    const int rg = t >> 2;
    const int cb = (t & 3) * 10;
    float acc[4][10];
    #pragma unroll
    for (int i = 0; i < 4; i++)
        #pragma unroll
        for (int j = 0; j < 10; j++) acc[i][j] = 0.f;

    for (int k0 = 0; k0 < 128; k0 += 16) {
        __syncthreads();
        #pragma unroll
        for (int i = 0; i < 4; i++) {
            int f = t + i * 256;
            int r = f >> 2, c = (f & 3) * 4;
            float4 hv = make_float4(0.f, 0.f, 0.f, 0.f);
            if (r0 + r < M)
                hv = *(const float4*)&H[(size_t)(r0 + r) * 128 + k0 + c];
            *(float4*)&Hs[r][c] = hv;
        }
        __syncthreads();
        #pragma unroll
        for (int k4 = 0; k4 < 4; k4++) {
            float hv[4][4];
            #pragma unroll
            for (int i = 0; i < 4; i++) {
                float4 h4 = *(const float4*)&Hs[rg + 64 * i][k4 * 4];
                hv[i][0] = h4.x; hv[i][1] = h4.y; hv[i][2] = h4.z; hv[i][3] = h4.w;
            }
            #pragma unroll
            for (int q = 0; q < 4; q++) {
                int k = k0 + k4 * 4 + q;
                float wv[10];
                #pragma unroll
                for (int j = 0; j < 5; j++) {
                    float2 w2 = *(const float2*)&Ws[k][cb + 2 * j];
                    wv[2 * j] = w2.x; wv[2 * j + 1] = w2.y;
                }
                #pragma unroll
                for (int i = 0; i < 4; i++)
                    #pragma unroll
                    for (int j = 0; j < 10; j++)
                        acc[i][j] = fmaf(hv[i][q], wv[j], acc[i][j]);
            }
        }
    }
    #pragma unroll
    for (int i = 0; i < 4; i++) {
        int row = r0 + rg + 64 * i;
        if (row < M) {
            #pragma unroll
            for (int j = 0; j < 10; j++)
                out[(size_t)row * 40 + cb + j] = acc[i][j] + b3[cb + j];
        }
    }
}

// ---------------- log_softmax (in place) + var partial sums ----------------
__global__ __launch_bounds__(256) void lsm_kernel(float* out, double* scal, int M) {
    const int wid  = threadIdx.x >> 6;
    const int lane = threadIdx.x & 63;
    float s1 = 0.f, s2 = 0.f;
    for (int r = blockIdx.x * 4 + wid; r < M; r += gridDim.x * 4) {
        size_t base = (size_t)r * 40;
        float x = (lane < 40) ? out[base + lane] : -INFINITY;
        float mx = x;
        #pragma unroll
        for (int o = 32; o; o >>= 1) mx = fmaxf(mx, __shfl_xor(mx, o));
        float e = (lane < 40) ? expf(x - mx) : 0.f;
        float se = e;
        #pragma unroll
        for (int o = 32; o; o >>= 1) se += __shfl_xor(se, o);
        float ls = mx + logf(se);
        if (lane < 40) {
            out[base + lane] = x - ls;
            s1 += x;
            s2 += x * x;
        }
    }
    #pragma unroll
    for (int o = 32; o; o >>= 1) { s1 += __shfl_xor(s1, o); s2 += __shfl_xor(s2, o); }
    __shared__ double sh1[4], sh2[4];
    if (lane == 0) { sh1[wid] = (double)s1; sh2[wid] = (double)s2; }
    __syncthreads();
    if (threadIdx.x == 0) {
        atomicAdd(&scal[0], sh1[0] + sh1[1] + sh1[2] + sh1[3]);
        atomicAdd(&scal[1], sh2[0] + sh2[1] + sh2[2] + sh2[3]);
    }
}

__global__ void var_kernel(const double* scal, float* out, long long nn, long long off) {
    double s1 = scal[0], s2 = scal[1];
    out[off] = (float)((s2 - s1 * s1 / (double)nn) / (double)(nn - 1));
}

// ---------------- launch ----------------
extern "C" void kernel_launch(void* const* d_in, const int* in_sizes, int n_in,
                              void* d_out, int out_size, void* d_ws, size_t ws_size,
                              hipStream_t stream) {
    const float* x   = (const float*)d_in[0];
    const void*  ei  = d_in[1];
    const float* W1  = (const float*)d_in[2];
    const float* b1  = (const float*)d_in[3];
    const float* g1  = (const float*)d_in[4];
    const float* be1 = (const float*)d_in[5];
    const float* m1  = (const float*)d_in[6];
    const float* v1  = (const float*)d_in[7];
    const float* W2  = (const float*)d_in[8];
    const float* b2  = (const float*)d_in[9];
    const float* g2  = (const float*)d_in[10];
    const float* be2 = (const float*)d_in[11];
    const float* m2  = (const float*)d_in[12];
    const float* v2  = (const float*)d_in[13];
    const float* W3  = (const float*)d_in[14];
    const float* b3  = (const float*)d_in[15];

    const int n = in_sizes[0] / 128;   // 169343 nodes
    const int E = in_sizes[1] / 2;     // 1166243 edges
    float* out = (float*)d_out;

    // workspace layout (all 16B-aligned):
    // scal[2] dbl | A[nh] | B[nh] | dinv[npad] | deg_i[npad] | rowptr[npad+4]
    // | cursor[npad] | bsum[128] | boff[128] | flag[4] | col[Epad]
    // | Wt1h | Wt1l | Wt2h | Wt2l  (each 128*128 ushort)
    size_t nh   = (size_t)n * 128;
    size_t npad = ((size_t)n + 3) & ~(size_t)3;
    size_t Epad = ((size_t)E + 3) & ~(size_t)3;
    double* scal   = (double*)d_ws;
    float*  A      = (float*)(scal + 2);
    float*  B      = A + nh;
    float*  dinv   = B + nh;
    int*    deg_i  = (int*)(dinv + npad);
    int*    rowptr = deg_i + npad;
    int*    cursor = rowptr + npad + 4;
    int*    bsum   = cursor + npad;
    int*    boff   = bsum + 128;
    int*    flag   = boff + 128;
    int*    col    = flag + 4;
    unsigned short* Wt1h = (unsigned short*)(col + Epad);
    unsigned short* Wt1l = Wt1h + 128 * 128;
    unsigned short* Wt2h = Wt1l + 128 * 128;
    unsigned short* Wt2l = Wt2h + 128 * 128;

    const int nb_n   = (n + 255) / 256;
    const int nb_e   = (E + 255) / 256;
    const int nb_gm  = (n + 127) / 128;
    const int nb_agg = (n + 3) / 4;
    const int nb_g3  = (n + 255) / 256;
    const int nb_sc  = (n + 2047) / 2048;

    detect_kernel<<<1, 1, 0, stream>>>(ei, flag);
    init_kernel<<<nb_n, 256, 0, stream>>>(deg_i, scal, n);
    degi_kernel<<<nb_e, 256, 0, stream>>>(ei, flag, deg_i, E);
    dinv_kernel<<<nb_n, 256, 0, stream>>>(deg_i, dinv, n);
    prep_w_kernel<<<64, 256, 0, stream>>>(W1, Wt1h, Wt1l);
    prep_w_kernel<<<64, 256, 0, stream>>>(W2, Wt2h, Wt2l);

    // CSR build
    scan1_kernel<<<nb_sc, 256, 0, stream>>>(deg_i, rowptr, bsum, n);
    scan1_kernel<<<1, 256, 0, stream>>>(bsum, boff, nullptr, nb_sc);
    scan3_kernel<<<nb_n, 256, 0, stream>>>(rowptr, boff, cursor, n, E);
    fill_kernel<<<nb_e, 256, 0, stream>>>(ei, flag, cursor, col, E);

    // layer 1
    gemm_mfma_kernel<<<nb_gm, 256, 0, stream>>>(x, Wt1h, Wt1l, dinv, A, n);
    agg_kernel<<<nb_agg, 256, 0, stream>>>(A, rowptr, col, dinv,
                                           b1, g1, be1, m1, v1, B, n);
    // layer 2
    gemm_mfma_kernel<<<nb_gm, 256, 0, stream>>>(B, Wt2h, Wt2l, dinv, A, n);
    agg_kernel<<<nb_agg, 256, 0, stream>>>(A, rowptr, col, dinv,
                                           b2, g2, be2, m2, v2, B, n);
    // output layer + fused epilogues
    gemm_out_kernel<<<nb_g3, 256, 0, stream>>>(B, W3, b3, out, n);
    lsm_kernel<<<2048, 256, 0, stream>>>(out, scal, n);
    var_kernel<<<1, 1, 0, stream>>>(scal, out, (long long)n * 40, (long long)n * 40);
}

// Round 7
// 598.923 us; speedup vs baseline: 7.3897x; 1.3386x over previous
//
#include <hip/hip_runtime.h>
#include <math.h>

#define BN_EPS 1e-5f

typedef _Float16 f16;
typedef __attribute__((ext_vector_type(2))) _Float16 f16x2;
typedef __attribute__((ext_vector_type(4))) _Float16 f16x4;
typedef __attribute__((ext_vector_type(8))) _Float16 f16x8;
typedef __attribute__((ext_vector_type(4))) float f32x4;

// ---------------- edge dtype handling (int32 vs int64) ----------------
__device__ __forceinline__ int edge_at(const void* ei, long long idx, int is64) {
    if (is64) return (int)((const long long*)ei)[idx];
    return ((const int*)ei)[idx];
}

__global__ void detect_kernel(const void* ei, int* flag) {
    const int* p = (const int*)ei;
    int f = 1;
    for (int i = 0; i < 64; i++)
        if (p[2 * i + 1] != 0) { f = 0; break; }
    *flag = f;
}

// ---------------- init: zero int-degrees + scalars ----------------
__global__ void init_kernel(int* deg_i, double* scal, int n) {
    int i = blockIdx.x * 256 + threadIdx.x;
    if (i < n) deg_i[i] = 0;
    if (blockIdx.x == 0 && threadIdx.x == 0) { scal[0] = 0.0; scal[1] = 0.0; }
}

__global__ void degi_kernel(const void* ei, const int* flag, int* deg_i, int E) {
    int e = blockIdx.x * 256 + threadIdx.x;
    if (e >= E) return;
    int is64 = *flag;
    int d = edge_at(ei, (long long)E + e, is64);
    atomicAdd(&deg_i[d], 1);
}

__global__ void dinv_kernel(const int* __restrict__ deg_i, float* dinv, int n) {
    int i = blockIdx.x * 256 + threadIdx.x;
    if (i < n) dinv[i] = rsqrtf((float)(deg_i[i] + 1));
}

// ---------------- exclusive scan (3 kernels, 2048 elems/block) -------------
__global__ __launch_bounds__(256) void scan1_kernel(
    const int* __restrict__ in, int* __restrict__ excl, int* bsum, int n) {
    __shared__ int sh[256];
    const int tid = threadIdx.x;
    const int base = blockIdx.x * 2048 + tid * 8;
    int v[8];
    #pragma unroll
    for (int i = 0; i < 8; i++) v[i] = (base + i < n) ? in[base + i] : 0;
    int tsum = 0;
    #pragma unroll
    for (int i = 0; i < 8; i++) { int t = v[i]; v[i] = tsum; tsum += t; }
    sh[tid] = tsum;
    __syncthreads();
    for (int off = 1; off < 256; off <<= 1) {
        int t = 0;
        if (tid >= off) t = sh[tid - off];
        __syncthreads();
        if (tid >= off) sh[tid] += t;
        __syncthreads();
    }
    int texcl = sh[tid] - tsum;
    #pragma unroll
    for (int i = 0; i < 8; i++)
        if (base + i < n) excl[base + i] = texcl + v[i];
    if (tid == 255 && bsum) bsum[blockIdx.x] = sh[255];
}

__global__ void scan3_kernel(int* rowptr, const int* __restrict__ boff,
                             int* cursor, int n, int E) {
    int i = blockIdx.x * 256 + threadIdx.x;
    if (i < n) {
        int val = rowptr[i] + boff[i >> 11];
        rowptr[i] = val;
        cursor[i] = val;
    }
    if (i == 0) rowptr[n] = E;
}

__global__ void fill_kernel(const void* ei, const int* flag,
                            int* cursor, int* col, int E) {
    int e = blockIdx.x * 256 + threadIdx.x;
    if (e >= E) return;
    int is64 = *flag;
    int s = edge_at(ei, e, is64);
    int d = edge_at(ei, (long long)E + e, is64);
    int pos = atomicAdd(&cursor[d], 1);
    col[pos] = s;
}

// ---------------- W prep: transpose + fp16 hi/lo split ----------------
__global__ __launch_bounds__(256) void prep_w_kernel(
    const float* __restrict__ W, f16* __restrict__ Wth, f16* __restrict__ Wtl) {
    for (int f = blockIdx.x * 256 + threadIdx.x; f < 128 * 128;
         f += gridDim.x * 256) {
        int k = f >> 7, nn = f & 127;
        float wv = W[f];
        f16 h = (f16)wv;
        f16 l = (f16)(wv - (float)h);
        Wth[nn * 128 + k] = h;
        Wtl[nn * 128 + k] = l;
    }
}

// ---------------- layer-1 MFMA GEMM: fp32 in, fp16 out, 3-pass ------------
// X@W = Xh@Wh + Xh@Wl + Xl@Wh (f16 hi/lo split; lo*lo ~2^-22 dropped).
#define APAD 40   // padded k-stride (halves): 80B rows
__global__ __launch_bounds__(256) void gemm_l1_kernel(
    const float* __restrict__ X, const f16* __restrict__ Wth,
    const f16* __restrict__ Wtl, const float* __restrict__ dinv,
    f16* __restrict__ out, int M) {
    __shared__ f16 Ah[128 * APAD];
    __shared__ f16 Al[128 * APAD];
    __shared__ f16 Bh[128 * APAD];
    __shared__ f16 Bl[128 * APAD];
    const int t = threadIdx.x;
    const int r0 = blockIdx.x * 128;
    const int w = t >> 6, lane = t & 63;
    const int m0 = (w >> 1) * 64, n0 = (w & 1) * 64;
    const int fr = lane & 15;
    const int kb = (lane >> 4) * 8;

    f32x4 acc[4][4];
    #pragma unroll
    for (int i = 0; i < 4; i++)
        #pragma unroll
        for (int j = 0; j < 4; j++) acc[i][j] = (f32x4)0.f;

    for (int k0 = 0; k0 < 128; k0 += 32) {
        #pragma unroll
        for (int i = 0; i < 4; i++) {
            int f = t + i * 256;               // 0..1023
            int row = f >> 3, kq = (f & 7) * 4;
            float4 v = make_float4(0.f, 0.f, 0.f, 0.f);
            if (r0 + row < M)
                v = *(const float4*)&X[(size_t)(r0 + row) * 128 + k0 + kq];
            f16 h0 = (f16)v.x, h1 = (f16)v.y, h2 = (f16)v.z, h3 = (f16)v.w;
            f16 l0 = (f16)(v.x - (float)h0), l1 = (f16)(v.y - (float)h1);
            f16 l2 = (f16)(v.z - (float)h2), l3 = (f16)(v.w - (float)h3);
            int base = row * APAD + kq;
            *(f16x4*)&Ah[base] = (f16x4){h0, h1, h2, h3};
            *(f16x4*)&Al[base] = (f16x4){l0, l1, l2, l3};
        }
        #pragma unroll
        for (int i = 0; i < 2; i++) {
            int f = t + i * 256;               // 0..511
            int nrow = f >> 2, kq = (f & 3) * 8;
            int gb = nrow * 128 + k0 + kq;
            int lb = nrow * APAD + kq;
            *(uint4*)&Bh[lb] = *(const uint4*)&Wth[gb];
            *(uint4*)&Bl[lb] = *(const uint4*)&Wtl[gb];
        }
        __syncthreads();

        f16x8 a0[4], b0[4], xx[4];
        #pragma unroll
        for (int i = 0; i < 4; i++) {
            a0[i] = *(const f16x8*)&Ah[(m0 + i * 16 + fr) * APAD + kb];
            b0[i] = *(const f16x8*)&Bh[(n0 + i * 16 + fr) * APAD + kb];
        }
        #pragma unroll
        for (int i = 0; i < 4; i++)
            #pragma unroll
            for (int j = 0; j < 4; j++)
                acc[i][j] = __builtin_amdgcn_mfma_f32_16x16x32_f16(
                    a0[i], b0[j], acc[i][j], 0, 0, 0);
        #pragma unroll
        for (int i = 0; i < 4; i++)
            xx[i] = *(const f16x8*)&Bl[(n0 + i * 16 + fr) * APAD + kb];
        #pragma unroll
        for (int i = 0; i < 4; i++)
            #pragma unroll
            for (int j = 0; j < 4; j++)
                acc[i][j] = __builtin_amdgcn_mfma_f32_16x16x32_f16(
                    a0[i], xx[j], acc[i][j], 0, 0, 0);
        #pragma unroll
        for (int i = 0; i < 4; i++)
            xx[i] = *(const f16x8*)&Al[(m0 + i * 16 + fr) * APAD + kb];
        #pragma unroll
        for (int i = 0; i < 4; i++)
            #pragma unroll
            for (int j = 0; j < 4; j++)
                acc[i][j] = __builtin_amdgcn_mfma_f32_16x16x32_f16(
                    xx[i], b0[j], acc[i][j], 0, 0, 0);
        __syncthreads();
    }

    // C/D layout: col=lane&15, row=(lane>>4)*4+reg (m89-verified)
    #pragma unroll
    for (int i = 0; i < 4; i++) {
        #pragma unroll
        for (int r = 0; r < 4; r++) {
            int row = r0 + m0 + i * 16 + (lane >> 4) * 4 + r;
            if (row < M) {
                float di = dinv[row];
                #pragma unroll
                for (int j = 0; j < 4; j++)
                    out[(size_t)row * 128 + n0 + j * 16 + fr] =
                        (f16)(acc[i][j][r] * di);
            }
        }
    }
}

// ---------------- layer-2 MFMA GEMM: fp16 in, fp16 out, 2-pass ------------
// X fp16 (storage-exact), W split hi/lo: X@W = X@Wh + X@Wl.
__global__ __launch_bounds__(256) void gemm_l2_kernel(
    const f16* __restrict__ X, const f16* __restrict__ Wth,
    const f16* __restrict__ Wtl, const float* __restrict__ dinv,
    f16* __restrict__ out, int M) {
    __shared__ f16 Ax[128 * APAD];
    __shared__ f16 Bh[128 * APAD];
    __shared__ f16 Bl[128 * APAD];
    const int t = threadIdx.x;
    const int r0 = blockIdx.x * 128;
    const int w = t >> 6, lane = t & 63;
    const int m0 = (w >> 1) * 64, n0 = (w & 1) * 64;
    const int fr = lane & 15;
    const int kb = (lane >> 4) * 8;

    f32x4 acc[4][4];
    #pragma unroll
    for (int i = 0; i < 4; i++)
        #pragma unroll
        for (int j = 0; j < 4; j++) acc[i][j] = (f32x4)0.f;

    for (int k0 = 0; k0 < 128; k0 += 32) {
        #pragma unroll
        for (int i = 0; i < 2; i++) {
            int f = t + i * 256;               // 0..511
            int row = f >> 2, kq = (f & 3) * 8;
            uint4 v = make_uint4(0u, 0u, 0u, 0u);
            if (r0 + row < M)
                v = *(const uint4*)&X[(size_t)(r0 + row) * 128 + k0 + kq];
            *(uint4*)&Ax[row * APAD + kq] = v;
        }
        #pragma unroll
        for (int i = 0; i < 2; i++) {
            int f = t + i * 256;
            int nrow = f >> 2, kq = (f & 3) * 8;
            int gb = nrow * 128 + k0 + kq;
            int lb = nrow * APAD + kq;
            *(uint4*)&Bh[lb] = *(const uint4*)&Wth[gb];
            *(uint4*)&Bl[lb] = *(const uint4*)&Wtl[gb];
        }
        __syncthreads();

        f16x8 a0[4], b0[4], xx[4];
        #pragma unroll
        for (int i = 0; i < 4; i++) {
            a0[i] = *(const f16x8*)&Ax[(m0 + i * 16 + fr) * APAD + kb];
            b0[i] = *(const f16x8*)&Bh[(n0 + i * 16 + fr) * APAD + kb];
        }
        #pragma unroll
        for (int i = 0; i < 4; i++)
            #pragma unroll
            for (int j = 0; j < 4; j++)
                acc[i][j] = __builtin_amdgcn_mfma_f32_16x16x32_f16(
                    a0[i], b0[j], acc[i][j], 0, 0, 0);
        #pragma unroll
        for (int i = 0; i < 4; i++)
            xx[i] = *(const f16x8*)&Bl[(n0 + i * 16 + fr) * APAD + kb];
        #pragma unroll
        for (int i = 0; i < 4; i++)
            #pragma unroll
            for (int j = 0; j < 4; j++)
                acc[i][j] = __builtin_amdgcn_mfma_f32_16x16x32_f16(
                    a0[i], xx[j], acc[i][j], 0, 0, 0);
        __syncthreads();
    }

    #pragma unroll
    for (int i = 0; i < 4; i++) {
        #pragma unroll
        for (int r = 0; r < 4; r++) {
            int row = r0 + m0 + i * 16 + (lane >> 4) * 4 + r;
            if (row < M) {
                float di = dinv[row];
                #pragma unroll
                for (int j = 0; j < 4; j++)
                    out[(size_t)row * 128 + n0 + j * 16 + fr] =
                        (f16)(acc[i][j][r] * di);
            }
        }
    }
}

// ---------------- fused pull-aggregate + bias + relu + BN + relu ----------
// Half-wave (32 lanes) per node; lane owns 4 channels (8B fp16 loads).
__global__ __launch_bounds__(256) void agg_kernel(
    const f16* __restrict__ hs, const int* __restrict__ rowptr,
    const int* __restrict__ col, const float* __restrict__ dinv,
    const float* __restrict__ b, const float* __restrict__ g,
    const float* __restrict__ be, const float* __restrict__ m,
    const float* __restrict__ v, f16* __restrict__ h, int M) {
    const int node = blockIdx.x * 8 + (threadIdx.x >> 5);
    if (node >= M) return;
    const int lane = threadIdx.x & 31;
    const int c = lane * 4;

    f16x4 sv = *(const f16x4*)&hs[(size_t)node * 128 + c];   // self-loop term
    float a1[4] = {(float)sv[0], (float)sv[1], (float)sv[2], (float)sv[3]};
    float a2[4] = {0.f, 0.f, 0.f, 0.f};
    const int beg = rowptr[node], end = rowptr[node + 1];
    int j = beg;
    for (; j + 1 < end; j += 2) {       // dual accumulators: 2 loads in flight
        int s0 = col[j], s1 = col[j + 1];
        f16x4 v0 = *(const f16x4*)&hs[(size_t)s0 * 128 + c];
        f16x4 v1 = *(const f16x4*)&hs[(size_t)s1 * 128 + c];
        #pragma unroll
        for (int q = 0; q < 4; q++) { a1[q] += (float)v0[q]; a2[q] += (float)v1[q]; }
    }
    if (j < end) {
        int s0 = col[j];
        f16x4 v0 = *(const f16x4*)&hs[(size_t)s0 * 128 + c];
        #pragma unroll
        for (int q = 0; q < 4; q++) a1[q] += (float)v0[q];
    }
    const float di = dinv[node];
    f16x4 r;
    #pragma unroll
    for (int q = 0; q < 4; q++) {
        int cc = c + q;
        float tt = fmaxf(di * (a1[q] + a2[q]) + b[cc], 0.f);
        tt = (tt - m[cc]) * (g[cc] * rsqrtf(v[cc] + BN_EPS)) + be[cc];
        r[q] = (f16)fmaxf(tt, 0.f);
    }
    *(f16x4*)&h[(size_t)node * 128 + c] = r;
}

// ------- output GEMM + fused log_softmax + var partials --------------------
// out_lsm = (H @ W3 + b3) - logsumexp_row;  s1/s2 accumulate raw logits.
__global__ __launch_bounds__(256) void gemm_out_kernel(
    const f16* __restrict__ H, const float* __restrict__ W3,
    const float* __restrict__ b3, float* __restrict__ out,
    double* __restrict__ scal, int M) {
    __shared__ float Hs[256][20];
    __shared__ float Ws[128][40];
    const int t  = threadIdx.x;
    const int r0 = blockIdx.x * 256;
    #pragma unroll
    for (int i = 0; i < 5; i++) {
        int f = t + i * 256;        // 1280 float4 = full W3
        ((float4*)Ws)[f] = ((const float4*)W3)[f];
    }
    const int rg = t >> 2;          // row group 0..63 (rows rg+64i)
    const int cb = (t & 3) * 10;    // 10-col slice; quad covers the 40 cols
    float acc[4][10];
    #pragma unroll
    for (int i = 0; i < 4; i++)
        #pragma unroll
        for (int j = 0; j < 10; j++) acc[i][j] = 0.f;

    for (int k0 = 0; k0 < 128; k0 += 16) {
        __syncthreads();            // also covers initial Ws store
        #pragma unroll
        for (int i = 0; i < 4; i++) {
            int f = t + i * 256;    // 1024 slots = 256x16 tile
            int r = f >> 2, c4 = (f & 3) * 4;
            float4 hv = make_float4(0.f, 0.f, 0.f, 0.f);
            if (r0 + r < M) {
                f16x4 hx = *(const f16x4*)&H[(size_t)(r0 + r) * 128 + k0 + c4];
                hv = make_float4((float)hx[0], (float)hx[1],
                                 (float)hx[2], (float)hx[3]);
            }
            *(float4*)&Hs[r][c4] = hv;
        }
        __syncthreads();
        #pragma unroll
        for (int k4 = 0; k4 < 4; k4++) {
            float hv[4][4];
            #pragma unroll
            for (int i = 0; i < 4; i++) {
                float4 h4 = *(const float4*)&Hs[rg + 64 * i][k4 * 4];
                hv[i][0] = h4.x; hv[i][1] = h4.y; hv[i][2] = h4.z; hv[i][3] = h4.w;
            }
            #pragma unroll
            for (int q = 0; q < 4; q++) {
                int k = k0 + k4 * 4 + q;
                float wv[10];
                #pragma unroll
                for (int j = 0; j < 5; j++) {
                    float2 w2 = *(const float2*)&Ws[k][cb + 2 * j];
                    wv[2 * j] = w2.x; wv[2 * j + 1] = w2.y;
                }
                #pragma unroll
                for (int i = 0; i < 4; i++)
                    #pragma unroll
                    for (int j = 0; j < 10; j++)
                        acc[i][j] = fmaf(hv[i][q], wv[j], acc[i][j]);
            }
        }
    }

    // fused epilogue: bias, quad-shuffle log_softmax, var partial sums
    float s1 = 0.f, s2 = 0.f;
    #pragma unroll
    for (int i = 0; i < 4; i++) {
        int row = r0 + rg + 64 * i;
        float vb[10];
        #pragma unroll
        for (int j = 0; j < 10; j++) vb[j] = acc[i][j] + b3[cb + j];
        float mx = vb[0];
        #pragma unroll
        for (int j = 1; j < 10; j++) mx = fmaxf(mx, vb[j]);
        mx = fmaxf(mx, __shfl_xor(mx, 1));     // quad lanes t^1, t^2 hold the
        mx = fmaxf(mx, __shfl_xor(mx, 2));     // other 30 cols of this row
        float se = 0.f;
        #pragma unroll
        for (int j = 0; j < 10; j++) se += expf(vb[j] - mx);
        se += __shfl_xor(se, 1);
        se += __shfl_xor(se, 2);
        float ls = mx + logf(se);
        if (row < M) {
            #pragma unroll
            for (int j = 0; j < 10; j++) {
                out[(size_t)row * 40 + cb + j] = vb[j] - ls;
                s1 += vb[j];
                s2 += vb[j] * vb[j];
            }
        }
    }
    #pragma unroll
    for (int o = 32; o; o >>= 1) { s1 += __shfl_xor(s1, o); s2 += __shfl_xor(s2, o); }
    __shared__ double sh1[4], sh2[4];
    if ((t & 63) == 0) { sh1[t >> 6] = (double)s1; sh2[t >> 6] = (double)s2; }
    __syncthreads();
    if (t == 0) {
        atomicAdd(&scal[0], sh1[0] + sh1[1] + sh1[2] + sh1[3]);
        atomicAdd(&scal[1], sh2[0] + sh2[1] + sh2[2] + sh2[3]);
    }
}

__global__ void var_kernel(const double* scal, float* out, long long nn, long long off) {
    double s1 = scal[0], s2 = scal[1];
    out[off] = (float)((s2 - s1 * s1 / (double)nn) / (double)(nn - 1));
}

// ---------------- launch ----------------
extern "C" void kernel_launch(void* const* d_in, const int* in_sizes, int n_in,
                              void* d_out, int out_size, void* d_ws, size_t ws_size,
                              hipStream_t stream) {
    const float* x   = (const float*)d_in[0];
    const void*  ei  = d_in[1];
    const float* W1  = (const float*)d_in[2];
    const float* b1  = (const float*)d_in[3];
    const float* g1  = (const float*)d_in[4];
    const float* be1 = (const float*)d_in[5];
    const float* m1  = (const float*)d_in[6];
    const float* v1  = (const float*)d_in[7];
    const float* W2  = (const float*)d_in[8];
    const float* b2  = (const float*)d_in[9];
    const float* g2  = (const float*)d_in[10];
    const float* be2 = (const float*)d_in[11];
    const float* m2  = (const float*)d_in[12];
    const float* v2  = (const float*)d_in[13];
    const float* W3  = (const float*)d_in[14];
    const float* b3  = (const float*)d_in[15];

    const int n = in_sizes[0] / 128;   // 169343 nodes
    const int E = in_sizes[1] / 2;     // 1166243 edges
    float* out = (float*)d_out;

    // workspace layout (all 16B-aligned):
    // scal[2] dbl | A[nh f16] | B[nh f16] | dinv[npad f32] | deg_i[npad]
    // | rowptr[npad+4] | cursor[npad] | bsum[128] | boff[128] | flag[4]
    // | col[Epad] | Wt1h | Wt1l | Wt2h | Wt2l  (each 128*128 f16)
    size_t nh   = (size_t)n * 128;
    size_t npad = ((size_t)n + 3) & ~(size_t)3;
    size_t Epad = ((size_t)E + 3) & ~(size_t)3;
    double* scal   = (double*)d_ws;
    f16*    A      = (f16*)(scal + 2);
    f16*    B      = A + nh;
    float*  dinv   = (float*)(B + nh);
    int*    deg_i  = (int*)(dinv + npad);
    int*    rowptr = deg_i + npad;
    int*    cursor = rowptr + npad + 4;
    int*    bsum   = cursor + npad;
    int*    boff   = bsum + 128;
    int*    flag   = boff + 128;
    int*    col    = flag + 4;
    f16*    Wt1h   = (f16*)(col + Epad);
    f16*    Wt1l   = Wt1h + 128 * 128;
    f16*    Wt2h   = Wt1l + 128 * 128;
    f16*    Wt2l   = Wt2h + 128 * 128;

    const int nb_n   = (n + 255) / 256;
    const int nb_e   = (E + 255) / 256;
    const int nb_gm  = (n + 127) / 128;
    const int nb_agg = (n + 7) / 8;
    const int nb_g3  = (n + 255) / 256;
    const int nb_sc  = (n + 2047) / 2048;

    detect_kernel<<<1, 1, 0, stream>>>(ei, flag);
    init_kernel<<<nb_n, 256, 0, stream>>>(deg_i, scal, n);
    degi_kernel<<<nb_e, 256, 0, stream>>>(ei, flag, deg_i, E);
    dinv_kernel<<<nb_n, 256, 0, stream>>>(deg_i, dinv, n);
    prep_w_kernel<<<64, 256, 0, stream>>>(W1, Wt1h, Wt1l);
    prep_w_kernel<<<64, 256, 0, stream>>>(W2, Wt2h, Wt2l);

    // CSR build
    scan1_kernel<<<nb_sc, 256, 0, stream>>>(deg_i, rowptr, bsum, n);
    scan1_kernel<<<1, 256, 0, stream>>>(bsum, boff, nullptr, nb_sc);
    scan3_kernel<<<nb_n, 256, 0, stream>>>(rowptr, boff, cursor, n, E);
    fill_kernel<<<nb_e, 256, 0, stream>>>(ei, flag, cursor, col, E);

    // layer 1
    gemm_l1_kernel<<<nb_gm, 256, 0, stream>>>(x, Wt1h, Wt1l, dinv, A, n);
    agg_kernel<<<nb_agg, 256, 0, stream>>>(A, rowptr, col, dinv,
                                           b1, g1, be1, m1, v1, B, n);
    // layer 2
    gemm_l2_kernel<<<nb_gm, 256, 0, stream>>>(B, Wt2h, Wt2l, dinv, A, n);
    agg_kernel<<<nb_agg, 256, 0, stream>>>(A, rowptr, col, dinv,
                                           b2, g2, be2, m2, v2, B, n);
    // output layer with fused log_softmax + var partials
    gemm_out_kernel<<<nb_g3, 256, 0, stream>>>(B, W3, b3, out, scal, n);
    var_kernel<<<1, 1, 0, stream>>>(scal, out, (long long)n * 40, (long long)n * 40);
}

// Round 8
// 565.549 us; speedup vs baseline: 7.8258x; 1.0590x over previous
//
#include <hip/hip_runtime.h>
#include <math.h>

#define BN_EPS 1e-5f

typedef _Float16 f16;
typedef __attribute__((ext_vector_type(4))) _Float16 f16x4;
typedef __attribute__((ext_vector_type(8))) _Float16 f16x8;
typedef __attribute__((ext_vector_type(4))) float f32x4;

// ---------------- edge dtype handling (int32 vs int64) ----------------
__device__ __forceinline__ int edge_at(const void* ei, long long idx, int is64) {
    if (is64) return (int)((const long long*)ei)[idx];
    return ((const int*)ei)[idx];
}

// ---------------- init: zero degrees + scalars + int64-detect --------------
__global__ void init_kernel(const void* ei, int* flag, int* deg_i,
                            double* scal, int n) {
    int i = blockIdx.x * 256 + threadIdx.x;
    if (i < n) deg_i[i] = 0;
    if (blockIdx.x == 0 && threadIdx.x == 0) {
        scal[0] = 0.0; scal[1] = 0.0;
        const int* p = (const int*)ei;
        int f = 1;
        for (int k = 0; k < 64; k++)
            if (p[2 * k + 1] != 0) { f = 0; break; }
        *flag = f;          // int64 iff every high word of 64 entries is 0
    }
}

__global__ void degi_kernel(const void* ei, const int* flag, int* deg_i, int E) {
    int e = blockIdx.x * 256 + threadIdx.x;
    if (e >= E) return;
    int is64 = *flag;
    int d = edge_at(ei, (long long)E + e, is64);
    atomicAdd(&deg_i[d], 1);
}

// ---------------- exclusive scan (2048 elems/block) ------------------------
__global__ __launch_bounds__(256) void scan1_kernel(
    const int* __restrict__ in, int* __restrict__ excl, int* bsum, int n) {
    __shared__ int sh[256];
    const int tid = threadIdx.x;
    const int base = blockIdx.x * 2048 + tid * 8;
    int v[8];
    #pragma unroll
    for (int i = 0; i < 8; i++) v[i] = (base + i < n) ? in[base + i] : 0;
    int tsum = 0;
    #pragma unroll
    for (int i = 0; i < 8; i++) { int t = v[i]; v[i] = tsum; tsum += t; }
    sh[tid] = tsum;
    __syncthreads();
    for (int off = 1; off < 256; off <<= 1) {
        int t = 0;
        if (tid >= off) t = sh[tid - off];
        __syncthreads();
        if (tid >= off) sh[tid] += t;
        __syncthreads();
    }
    int texcl = sh[tid] - tsum;
    #pragma unroll
    for (int i = 0; i < 8; i++)
        if (base + i < n) excl[base + i] = texcl + v[i];
    if (tid == 255 && bsum) bsum[blockIdx.x] = sh[255];
}

// scan3 + dinv fused (deg_i still live, so dinv computed here)
__global__ void scan3_kernel(int* rowptr, const int* __restrict__ boff,
                             int* cursor, const int* __restrict__ deg_i,
                             float* __restrict__ dinv, int n, int E) {
    int i = blockIdx.x * 256 + threadIdx.x;
    if (i < n) {
        int val = rowptr[i] + boff[i >> 11];
        rowptr[i] = val;
        cursor[i] = val;
        dinv[i] = rsqrtf((float)(deg_i[i] + 1));   // +1 self-loop
    }
    if (i == 0) rowptr[n] = E;
}

__global__ void fill_kernel(const void* ei, const int* flag,
                            int* cursor, int* col, int E) {
    int e = blockIdx.x * 256 + threadIdx.x;
    if (e >= E) return;
    int is64 = *flag;
    int s = edge_at(ei, e, is64);
    int d = edge_at(ei, (long long)E + e, is64);
    int pos = atomicAdd(&cursor[d], 1);
    col[pos] = s;
}

// ---------------- W prep: transpose + fp16 hi/lo split ----------------
__global__ __launch_bounds__(256) void prep_w_kernel(
    const float* __restrict__ W, f16* __restrict__ Wth, f16* __restrict__ Wtl) {
    for (int f = blockIdx.x * 256 + threadIdx.x; f < 128 * 128;
         f += gridDim.x * 256) {
        int k = f >> 7, nn = f & 127;
        float wv = W[f];
        f16 h = (f16)wv;
        f16 l = (f16)(wv - (float)h);
        Wth[nn * 128 + k] = h;
        Wtl[nn * 128 + k] = l;
    }
}

// ---------------- layer-1 MFMA GEMM: fp32 in, fp16 out, 2-pass ------------
// X@W ≈ Xh@Wh + Xh@Wl = Xh@W ; Xh rounding (2^-11) == output f16 rounding.
#define APAD 40   // padded k-stride (halves): 80B rows
__global__ __launch_bounds__(256) void gemm_l1_kernel(
    const float* __restrict__ X, const f16* __restrict__ Wth,
    const f16* __restrict__ Wtl, const float* __restrict__ dinv,
    f16* __restrict__ out, int M) {
    __shared__ f16 Ah[128 * APAD];
    __shared__ f16 Bh[128 * APAD];
    __shared__ f16 Bl[128 * APAD];
    const int t = threadIdx.x;
    const int r0 = blockIdx.x * 128;
    const int w = t >> 6, lane = t & 63;
    const int m0 = (w >> 1) * 64, n0 = (w & 1) * 64;
    const int fr = lane & 15;
    const int kb = (lane >> 4) * 8;

    f32x4 acc[4][4];
    #pragma unroll
    for (int i = 0; i < 4; i++)
        #pragma unroll
        for (int j = 0; j < 4; j++) acc[i][j] = (f32x4)0.f;

    for (int k0 = 0; k0 < 128; k0 += 32) {
        #pragma unroll
        for (int i = 0; i < 4; i++) {
            int f = t + i * 256;               // 0..1023
            int row = f >> 3, kq = (f & 7) * 4;
            float4 v = make_float4(0.f, 0.f, 0.f, 0.f);
            if (r0 + row < M)
                v = *(const float4*)&X[(size_t)(r0 + row) * 128 + k0 + kq];
            *(f16x4*)&Ah[row * APAD + kq] =
                (f16x4){(f16)v.x, (f16)v.y, (f16)v.z, (f16)v.w};
        }
        #pragma unroll
        for (int i = 0; i < 2; i++) {
            int f = t + i * 256;               // 0..511
            int nrow = f >> 2, kq = (f & 3) * 8;
            int gb = nrow * 128 + k0 + kq;
            int lb = nrow * APAD + kq;
            *(uint4*)&Bh[lb] = *(const uint4*)&Wth[gb];
            *(uint4*)&Bl[lb] = *(const uint4*)&Wtl[gb];
        }
        __syncthreads();

        f16x8 a0[4], b0[4], xx[4];
        #pragma unroll
        for (int i = 0; i < 4; i++) {
            a0[i] = *(const f16x8*)&Ah[(m0 + i * 16 + fr) * APAD + kb];
            b0[i] = *(const f16x8*)&Bh[(n0 + i * 16 + fr) * APAD + kb];
        }
        #pragma unroll
        for (int i = 0; i < 4; i++)
            #pragma unroll
            for (int j = 0; j < 4; j++)
                acc[i][j] = __builtin_amdgcn_mfma_f32_16x16x32_f16(
                    a0[i], b0[j], acc[i][j], 0, 0, 0);
        #pragma unroll
        for (int i = 0; i < 4; i++)
            xx[i] = *(const f16x8*)&Bl[(n0 + i * 16 + fr) * APAD + kb];
        #pragma unroll
        for (int i = 0; i < 4; i++)
            #pragma unroll
            for (int j = 0; j < 4; j++)
                acc[i][j] = __builtin_amdgcn_mfma_f32_16x16x32_f16(
                    a0[i], xx[j], acc[i][j], 0, 0, 0);
        __syncthreads();
    }

    // C/D layout: col=lane&15, row=(lane>>4)*4+reg (m89-verified)
    #pragma unroll
    for (int i = 0; i < 4; i++) {
        #pragma unroll
        for (int r = 0; r < 4; r++) {
            int row = r0 + m0 + i * 16 + (lane >> 4) * 4 + r;
            if (row < M) {
                float di = dinv[row];
                #pragma unroll
                for (int j = 0; j < 4; j++)
                    out[(size_t)row * 128 + n0 + j * 16 + fr] =
                        (f16)(acc[i][j][r] * di);
            }
        }
    }
}

// ---------------- layer-2 MFMA GEMM: fp16 in, fp16 out, 2-pass ------------
__global__ __launch_bounds__(256) void gemm_l2_kernel(
    const f16* __restrict__ X, const f16* __restrict__ Wth,
    const f16* __restrict__ Wtl, const float* __restrict__ dinv,
    f16* __restrict__ out, int M) {
    __shared__ f16 Ax[128 * APAD];
    __shared__ f16 Bh[128 * APAD];
    __shared__ f16 Bl[128 * APAD];
    const int t = threadIdx.x;
    const int r0 = blockIdx.x * 128;
    const int w = t >> 6, lane = t & 63;
    const int m0 = (w >> 1) * 64, n0 = (w & 1) * 64;
    const int fr = lane & 15;
    const int kb = (lane >> 4) * 8;

    f32x4 acc[4][4];
    #pragma unroll
    for (int i = 0; i < 4; i++)
        #pragma unroll
        for (int j = 0; j < 4; j++) acc[i][j] = (f32x4)0.f;

    for (int k0 = 0; k0 < 128; k0 += 32) {
        #pragma unroll
        for (int i = 0; i < 2; i++) {
            int f = t + i * 256;               // 0..511
            int row = f >> 2, kq = (f & 3) * 8;
            uint4 v = make_uint4(0u, 0u, 0u, 0u);
            if (r0 + row < M)
                v = *(const uint4*)&X[(size_t)(r0 + row) * 128 + k0 + kq];
            *(uint4*)&Ax[row * APAD + kq] = v;
        }
        #pragma unroll
        for (int i = 0; i < 2; i++) {
            int f = t + i * 256;
            int nrow = f >> 2, kq = (f & 3) * 8;
            int gb = nrow * 128 + k0 + kq;
            int lb = nrow * APAD + kq;
            *(uint4*)&Bh[lb] = *(const uint4*)&Wth[gb];
            *(uint4*)&Bl[lb] = *(const uint4*)&Wtl[gb];
        }
        __syncthreads();

        f16x8 a0[4], b0[4], xx[4];
        #pragma unroll
        for (int i = 0; i < 4; i++) {
            a0[i] = *(const f16x8*)&Ax[(m0 + i * 16 + fr) * APAD + kb];
            b0[i] = *(const f16x8*)&Bh[(n0 + i * 16 + fr) * APAD + kb];
        }
        #pragma unroll
        for (int i = 0; i < 4; i++)
            #pragma unroll
            for (int j = 0; j < 4; j++)
                acc[i][j] = __builtin_amdgcn_mfma_f32_16x16x32_f16(
                    a0[i], b0[j], acc[i][j], 0, 0, 0);
        #pragma unroll
        for (int i = 0; i < 4; i++)
            xx[i] = *(const f16x8*)&Bl[(n0 + i * 16 + fr) * APAD + kb];
        #pragma unroll
        for (int i = 0; i < 4; i++)
            #pragma unroll
            for (int j = 0; j < 4; j++)
                acc[i][j] = __builtin_amdgcn_mfma_f32_16x16x32_f16(
                    a0[i], xx[j], acc[i][j], 0, 0, 0);
        __syncthreads();
    }

    #pragma unroll
    for (int i = 0; i < 4; i++) {
        #pragma unroll
        for (int r = 0; r < 4; r++) {
            int row = r0 + m0 + i * 16 + (lane >> 4) * 4 + r;
            if (row < M) {
                float di = dinv[row];
                #pragma unroll
                for (int j = 0; j < 4; j++)
                    out[(size_t)row * 128 + n0 + j * 16 + fr] =
                        (f16)(acc[i][j][r] * di);
            }
        }
    }
}

// ---------------- fused pull-aggregate + bias + relu + BN + relu ----------
// Half-wave (32 lanes) per node; 4-deep ILP: 4 gathers in flight.
__global__ __launch_bounds__(256) void agg_kernel(
    const f16* __restrict__ hs, const int* __restrict__ rowptr,
    const int* __restrict__ col, const float* __restrict__ dinv,
    const float* __restrict__ b, const float* __restrict__ g,
    const float* __restrict__ be, const float* __restrict__ m,
    const float* __restrict__ v, f16* __restrict__ h, int M) {
    const int node = blockIdx.x * 8 + (threadIdx.x >> 5);
    if (node >= M) return;
    const int lane = threadIdx.x & 31;
    const int c = lane * 4;
    const f16* __restrict__ base = hs + c;

    f16x4 sv = *(const f16x4*)&base[(size_t)node * 128];   // self-loop term
    float a0[4] = {(float)sv[0], (float)sv[1], (float)sv[2], (float)sv[3]};
    float a1[4] = {0.f, 0.f, 0.f, 0.f};
    float a2[4] = {0.f, 0.f, 0.f, 0.f};
    float a3[4] = {0.f, 0.f, 0.f, 0.f};
    const int beg = rowptr[node], end = rowptr[node + 1];
    int j = beg;
    for (; j + 3 < end; j += 4) {       // 4 independent loads in flight
        int s0 = col[j], s1 = col[j + 1], s2 = col[j + 2], s3 = col[j + 3];
        f16x4 v0 = *(const f16x4*)&base[(size_t)s0 * 128];
        f16x4 v1 = *(const f16x4*)&base[(size_t)s1 * 128];
        f16x4 v2 = *(const f16x4*)&base[(size_t)s2 * 128];
        f16x4 v3 = *(const f16x4*)&base[(size_t)s3 * 128];
        #pragma unroll
        for (int q = 0; q < 4; q++) {
            a0[q] += (float)v0[q]; a1[q] += (float)v1[q];
            a2[q] += (float)v2[q]; a3[q] += (float)v3[q];
        }
    }
    if (j + 1 < end) {                  // 2-tail
        int s0 = col[j], s1 = col[j + 1];
        f16x4 v0 = *(const f16x4*)&base[(size_t)s0 * 128];
        f16x4 v1 = *(const f16x4*)&base[(size_t)s1 * 128];
        #pragma unroll
        for (int q = 0; q < 4; q++) { a0[q] += (float)v0[q]; a1[q] += (float)v1[q]; }
        j += 2;
    }
    if (j < end) {                      // 1-tail
        int s0 = col[j];
        f16x4 v0 = *(const f16x4*)&base[(size_t)s0 * 128];
        #pragma unroll
        for (int q = 0; q < 4; q++) a0[q] += (float)v0[q];
    }
    const float di = dinv[node];
    f16x4 r;
    #pragma unroll
    for (int q = 0; q < 4; q++) {
        int cc = c + q;
        float s = (a0[q] + a1[q]) + (a2[q] + a3[q]);
        float tt = fmaxf(di * s + b[cc], 0.f);
        tt = (tt - m[cc]) * (g[cc] * rsqrtf(v[cc] + BN_EPS)) + be[cc];
        r[q] = (f16)fmaxf(tt, 0.f);
    }
    *(f16x4*)&h[(size_t)node * 128 + c] = r;
}

// ------- output GEMM + fused log_softmax + var partials --------------------
__global__ __launch_bounds__(256) void gemm_out_kernel(
    const f16* __restrict__ H, const float* __restrict__ W3,
    const float* __restrict__ b3, float* __restrict__ out,
    double* __restrict__ scal, int M) {
    __shared__ float Hs[256][20];
    __shared__ float Ws[128][40];
    const int t  = threadIdx.x;
    const int r0 = blockIdx.x * 256;
    #pragma unroll
    for (int i = 0; i < 5; i++) {
        int f = t + i * 256;        // 1280 float4 = full W3
        ((float4*)Ws)[f] = ((const float4*)W3)[f];
    }
    const int rg = t >> 2;          // row group 0..63 (rows rg+64i)
    const int cb = (t & 3) * 10;    // 10-col slice; quad covers the 40 cols
    float acc[4][10];
    #pragma unroll
    for (int i = 0; i < 4; i++)
        #pragma unroll
        for (int j = 0; j < 10; j++) acc[i][j] = 0.f;

    for (int k0 = 0; k0 < 128; k0 += 16) {
        __syncthreads();            // also covers initial Ws store
        #pragma unroll
        for (int i = 0; i < 4; i++) {
            int f = t + i * 256;    // 1024 slots = 256x16 tile
            int r = f >> 2, c4 = (f & 3) * 4;
            float4 hv = make_float4(0.f, 0.f, 0.f, 0.f);
            if (r0 + r < M) {
                f16x4 hx = *(const f16x4*)&H[(size_t)(r0 + r) * 128 + k0 + c4];
                hv = make_float4((float)hx[0], (float)hx[1],
                                 (float)hx[2], (float)hx[3]);
            }
            *(float4*)&Hs[r][c4] = hv;
        }
        __syncthreads();
        #pragma unroll
        for (int k4 = 0; k4 < 4; k4++) {
            float hv[4][4];
            #pragma unroll
            for (int i = 0; i < 4; i++) {
                float4 h4 = *(const float4*)&Hs[rg + 64 * i][k4 * 4];
                hv[i][0] = h4.x; hv[i][1] = h4.y; hv[i][2] = h4.z; hv[i][3] = h4.w;
            }
            #pragma unroll
            for (int q = 0; q < 4; q++) {
                int k = k0 + k4 * 4 + q;
                float wv[10];
                #pragma unroll
                for (int j = 0; j < 5; j++) {
                    float2 w2 = *(const float2*)&Ws[k][cb + 2 * j];
                    wv[2 * j] = w2.x; wv[2 * j + 1] = w2.y;
                }
                #pragma unroll
                for (int i = 0; i < 4; i++)
                    #pragma unroll
                    for (int j = 0; j < 10; j++)
                        acc[i][j] = fmaf(hv[i][q], wv[j], acc[i][j]);
            }
        }
    }

    // fused epilogue: bias, quad-shuffle log_softmax, var partial sums
    float s1 = 0.f, s2 = 0.f;
    #pragma unroll
    for (int i = 0; i < 4; i++) {
        int row = r0 + rg + 64 * i;
        float vb[10];
        #pragma unroll
        for (int j = 0; j < 10; j++) vb[j] = acc[i][j] + b3[cb + j];
        float mx = vb[0];
        #pragma unroll
        for (int j = 1; j < 10; j++) mx = fmaxf(mx, vb[j]);
        mx = fmaxf(mx, __shfl_xor(mx, 1));
        mx = fmaxf(mx, __shfl_xor(mx, 2));
        float se = 0.f;
        #pragma unroll
        for (int j = 0; j < 10; j++) se += expf(vb[j] - mx);
        se += __shfl_xor(se, 1);
        se += __shfl_xor(se, 2);
        float ls = mx + logf(se);
        if (row < M) {
            #pragma unroll
            for (int j = 0; j < 10; j++) {
                out[(size_t)row * 40 + cb + j] = vb[j] - ls;
                s1 += vb[j];
                s2 += vb[j] * vb[j];
            }
        }
    }
    #pragma unroll
    for (int o = 32; o; o >>= 1) { s1 += __shfl_xor(s1, o); s2 += __shfl_xor(s2, o); }
    __shared__ double sh1[4], sh2[4];
    if ((t & 63) == 0) { sh1[t >> 6] = (double)s1; sh2[t >> 6] = (double)s2; }
    __syncthreads();
    if (t == 0) {
        atomicAdd(&scal[0], sh1[0] + sh1[1] + sh1[2] + sh1[3]);
        atomicAdd(&scal[1], sh2[0] + sh2[1] + sh2[2] + sh2[3]);
    }
}

__global__ void var_kernel(const double* scal, float* out, long long nn, long long off) {
    double s1 = scal[0], s2 = scal[1];
    out[off] = (float)((s2 - s1 * s1 / (double)nn) / (double)(nn - 1));
}

// ---------------- launch ----------------
extern "C" void kernel_launch(void* const* d_in, const int* in_sizes, int n_in,
                              void* d_out, int out_size, void* d_ws, size_t ws_size,
                              hipStream_t stream) {
    const float* x   = (const float*)d_in[0];
    const void*  ei  = d_in[1];
    const float* W1  = (const float*)d_in[2];
    const float* b1  = (const float*)d_in[3];
    const float* g1  = (const float*)d_in[4];
    const float* be1 = (const float*)d_in[5];
    const float* m1  = (const float*)d_in[6];
    const float* v1  = (const float*)d_in[7];
    const float* W2  = (const float*)d_in[8];
    const float* b2  = (const float*)d_in[9];
    const float* g2  = (const float*)d_in[10];
    const float* be2 = (const float*)d_in[11];
    const float* m2  = (const float*)d_in[12];
    const float* v2  = (const float*)d_in[13];
    const float* W3  = (const float*)d_in[14];
    const float* b3  = (const float*)d_in[15];

    const int n = in_sizes[0] / 128;   // 169343 nodes
    const int E = in_sizes[1] / 2;     // 1166243 edges
    float* out = (float*)d_out;

    // workspace layout (all 16B-aligned):
    // scal[2] dbl | A[nh f16] | B[nh f16] | dinv[npad f32] | deg_i[npad]
    // | rowptr[npad+4] | cursor[npad] | bsum[128] | boff[128] | flag[4]
    // | col[Epad] | Wt1h | Wt1l | Wt2h | Wt2l  (each 128*128 f16)
    size_t nh   = (size_t)n * 128;
    size_t npad = ((size_t)n + 3) & ~(size_t)3;
    size_t Epad = ((size_t)E + 3) & ~(size_t)3;
    double* scal   = (double*)d_ws;
    f16*    A      = (f16*)(scal + 2);
    f16*    B      = A + nh;
    float*  dinv   = (float*)(B + nh);
    int*    deg_i  = (int*)(dinv + npad);
    int*    rowptr = deg_i + npad;
    int*    cursor = rowptr + npad + 4;
    int*    bsum   = cursor + npad;
    int*    boff   = bsum + 128;
    int*    flag   = boff + 128;
    int*    col    = flag + 4;
    f16*    Wt1h   = (f16*)(col + Epad);
    f16*    Wt1l   = Wt1h + 128 * 128;
    f16*    Wt2h   = Wt1l + 128 * 128;
    f16*    Wt2l   = Wt2h + 128 * 128;

    const int nb_n   = (n + 255) / 256;
    const int nb_e   = (E + 255) / 256;
    const int nb_gm  = (n + 127) / 128;
    const int nb_agg = (n + 7) / 8;
    const int nb_g3  = (n + 255) / 256;
    const int nb_sc  = (n + 2047) / 2048;

    init_kernel<<<nb_n, 256, 0, stream>>>(ei, flag, deg_i, scal, n);
    degi_kernel<<<nb_e, 256, 0, stream>>>(ei, flag, deg_i, E);
    prep_w_kernel<<<64, 256, 0, stream>>>(W1, Wt1h, Wt1l);
    prep_w_kernel<<<64, 256, 0, stream>>>(W2, Wt2h, Wt2l);

    // CSR build (scan3 also computes dinv from deg_i)
    scan1_kernel<<<nb_sc, 256, 0, stream>>>(deg_i, rowptr, bsum, n);
    scan1_kernel<<<1, 256, 0, stream>>>(bsum, boff, nullptr, nb_sc);
    scan3_kernel<<<nb_n, 256, 0, stream>>>(rowptr, boff, cursor, deg_i, dinv, n, E);
    fill_kernel<<<nb_e, 256, 0, stream>>>(ei, flag, cursor, col, E);

    // layer 1
    gemm_l1_kernel<<<nb_gm, 256, 0, stream>>>(x, Wt1h, Wt1l, dinv, A, n);
    agg_kernel<<<nb_agg, 256, 0, stream>>>(A, rowptr, col, dinv,
                                           b1, g1, be1, m1, v1, B, n);
    // layer 2
    gemm_l2_kernel<<<nb_gm, 256, 0, stream>>>(B, Wt2h, Wt2l, dinv, A, n);
    agg_kernel<<<nb_agg, 256, 0, stream>>>(A, rowptr, col, dinv,
                                           b2, g2, be2, m2, v2, B, n);
    // output layer with fused log_softmax + var partials
    gemm_out_kernel<<<nb_g3, 256, 0, stream>>>(B, W3, b3, out, scal, n);
    var_kernel<<<1, 1, 0, stream>>>(scal, out, (long long)n * 40, (long long)n * 40);
}